// Round 1
// baseline (7951.000 us; speedup 1.0000x reference)
//
#include <hip/hip_runtime.h>

#define TPB 256

// ---------------------------------------------------------------------------
// DWT: x [16,8,256,256] -> out [16,32,128,128], channel = c*4 + s
// c[b,c,s,h,w] = sum_{d,e} x[b,c,2h+d,2w+e] * Kd[s,d,e]
// ---------------------------------------------------------------------------
__global__ __launch_bounds__(TPB) void dwt_kernel(const float* __restrict__ x,
                                                  const float* __restrict__ Kd,
                                                  float* __restrict__ out) {
    int idx = blockIdx.x * TPB + threadIdx.x;        // over 16*8*128*128
    int w = idx & 127, h = (idx >> 7) & 127, bc = idx >> 14;   // bc = b*8+c
    const float2* row0 = (const float2*)(x + ((size_t)bc << 16) + ((size_t)(h << 1) << 8)) + w;
    const float2* row1 = row0 + 128;
    float2 r0 = *row0, r1 = *row1;
    float k[16];
#pragma unroll
    for (int i = 0; i < 16; ++i) k[i] = Kd[i];
    size_t obase = ((size_t)(bc << 2) << 14) + (h << 7) + w;
#pragma unroll
    for (int s = 0; s < 4; ++s) {
        float v = r0.x * k[s*4+0] + r0.y * k[s*4+1] + r1.x * k[s*4+2] + r1.y * k[s*4+3];
        out[obase + ((size_t)s << 14)] = v;
    }
}

// ---------------------------------------------------------------------------
// IDWT: c [16,16,128,128] -> out [16,4,256,256]
// y[b,c,2h+d,2w+e] = sum_s c[b, c*4+s, h, w] * Kr[s,d,e]
// ---------------------------------------------------------------------------
__global__ __launch_bounds__(TPB) void idwt_kernel(const float* __restrict__ c,
                                                   const float* __restrict__ Kr,
                                                   float* __restrict__ out) {
    int idx = blockIdx.x * TPB + threadIdx.x;        // over 16*4*128*128
    int w = idx & 127, h = (idx >> 7) & 127, bc = idx >> 14;   // bc = b*4+c
    size_t ibase = ((size_t)(bc << 2) << 14) + (h << 7) + w;
    float cs[4];
#pragma unroll
    for (int s = 0; s < 4; ++s) cs[s] = c[ibase + ((size_t)s << 14)];
    float k[16];
#pragma unroll
    for (int i = 0; i < 16; ++i) k[i] = Kr[i];
    float y00 = 0, y01 = 0, y10 = 0, y11 = 0;
#pragma unroll
    for (int s = 0; s < 4; ++s) {
        y00 += cs[s] * k[s*4+0]; y01 += cs[s] * k[s*4+1];
        y10 += cs[s] * k[s*4+2]; y11 += cs[s] * k[s*4+3];
    }
    float2* o0 = (float2*)(out + ((size_t)bc << 16) + ((size_t)(h << 1) << 8)) + w;
    float2* o1 = o0 + 128;
    *o0 = make_float2(y00, y01);
    *o1 = make_float2(y10, y11);
}

// ---------------------------------------------------------------------------
// block-level sum/sumsq reduction -> one atomicAdd pair per block
// ---------------------------------------------------------------------------
__device__ __forceinline__ void block_stats_atomic(float lsum, float lss,
                                                   float* red, float2* slot) {
    int tid = threadIdx.x;
    red[tid] = lsum;
    red[TPB + tid] = lss;
    __syncthreads();
    for (int s = TPB / 2; s > 0; s >>= 1) {
        if (tid < s) {
            red[tid] += red[tid + s];
            red[TPB + tid] += red[TPB + tid + s];
        }
        __syncthreads();
    }
    if (tid == 0) {
        atomicAdd(&slot->x, red[0]);
        atomicAdd(&slot->y, red[TPB]);
    }
}

// ---------------------------------------------------------------------------
// 3x3 stride-1 pad-1 conv + bias (+ optional GN stats accumulation).
// Output tile 64(H) x 16(W) per block; 256 threads; 4 output rows per thread.
// ---------------------------------------------------------------------------
template<int CIN, int COUT, int H, int W, bool STATS>
__global__ __launch_bounds__(TPB) void conv3x3_s1(const float* __restrict__ in,
                                                  const float* __restrict__ wgt,
                                                  const float* __restrict__ bias,
                                                  float* __restrict__ outp,
                                                  float2* __restrict__ stats) {
    constexpr int TH = 64, TW = 16;
    constexpr int NTH = H / TH, NTW = W / TW;
    constexpr int LC = TW + 2;                 // 18
    __shared__ float tile[(TH + 2) * LC];      // 66*18
    __shared__ float red[2 * TPB];
    int blk = blockIdx.x;
    int tw = blk % NTW; blk /= NTW;
    int th = blk % NTH; blk /= NTH;
    int co = blk % COUT;
    int b  = blk / COUT;
    int tid = threadIdx.x;
    int tx = tid & 15, ty = tid >> 4;          // ty in [0,16)
    int oh0 = th * TH, ow0 = tw * TW;
    float acc0 = 0, acc1 = 0, acc2 = 0, acc3 = 0;
    const float* xin = in + (size_t)(b * CIN) * (H * W);
    const float* wp  = wgt + (size_t)co * (CIN * 9);
    for (int ci = 0; ci < CIN; ++ci) {
        const float* xc = xin + (size_t)ci * (H * W);
        for (int i = tid; i < (TH + 2) * LC; i += TPB) {
            int rr = i / LC, cc = i - rr * LC;
            int gh = oh0 - 1 + rr, gw = ow0 - 1 + cc;
            float v = 0.f;
            if ((unsigned)gh < (unsigned)H && (unsigned)gw < (unsigned)W)
                v = xc[gh * W + gw];
            tile[i] = v;
        }
        __syncthreads();
        const float* wc = wp + ci * 9;
        float w0 = wc[0], w1 = wc[1], w2 = wc[2],
              w3 = wc[3], w4 = wc[4], w5 = wc[5],
              w6 = wc[6], w7 = wc[7], w8 = wc[8];
        int base = (ty * 4) * LC + tx;
#pragma unroll
        for (int kw = 0; kw < 3; ++kw) {
            float c0 = tile[base + 0 * LC + kw];
            float c1 = tile[base + 1 * LC + kw];
            float c2 = tile[base + 2 * LC + kw];
            float c3 = tile[base + 3 * LC + kw];
            float c4 = tile[base + 4 * LC + kw];
            float c5 = tile[base + 5 * LC + kw];
            float wk0 = (kw == 0 ? w0 : kw == 1 ? w1 : w2);
            float wk1 = (kw == 0 ? w3 : kw == 1 ? w4 : w5);
            float wk2 = (kw == 0 ? w6 : kw == 1 ? w7 : w8);
            acc0 += c0 * wk0 + c1 * wk1 + c2 * wk2;
            acc1 += c1 * wk0 + c2 * wk1 + c3 * wk2;
            acc2 += c2 * wk0 + c3 * wk1 + c4 * wk2;
            acc3 += c3 * wk0 + c4 * wk1 + c5 * wk2;
        }
        __syncthreads();
    }
    float bv = bias[co];
    acc0 += bv; acc1 += bv; acc2 += bv; acc3 += bv;
    int oh = oh0 + ty * 4;
    size_t obase = ((size_t)(b * COUT + co) * H + oh) * W + ow0 + tx;
    outp[obase]         = acc0;
    outp[obase + W]     = acc1;
    outp[obase + 2 * W] = acc2;
    outp[obase + 3 * W] = acc3;
    if (STATS) {
        float ls  = acc0 + acc1 + acc2 + acc3;
        float lss = acc0 * acc0 + acc1 * acc1 + acc2 * acc2 + acc3 * acc3;
        block_stats_atomic(ls, lss, red, &stats[(size_t)b * (COUT / 8) + (co >> 3)]);
    }
}

// ---------------------------------------------------------------------------
// 3x3 stride-2 pad-1 conv + bias + GN stats.
// Output tile 32x32 per block; 256 threads (32 tx, 8 ty), 4 output rows/thread.
// ---------------------------------------------------------------------------
template<int CIN, int COUT, int HIN, int WIN, bool STATS>
__global__ __launch_bounds__(TPB) void conv3x3_s2(const float* __restrict__ in,
                                                  const float* __restrict__ wgt,
                                                  const float* __restrict__ bias,
                                                  float* __restrict__ outp,
                                                  float2* __restrict__ stats) {
    constexpr int HOUT = HIN / 2, WOUT = WIN / 2;
    constexpr int TH = 32, TW = 32;
    constexpr int NTH = HOUT / TH, NTW = WOUT / TW;
    constexpr int LR = 2 * TH + 1, LC = 2 * TW + 2;   // 65 x 66
    __shared__ float tile[LR * LC];
    __shared__ float red[2 * TPB];
    int blk = blockIdx.x;
    int tw = blk % NTW; blk /= NTW;
    int th = blk % NTH; blk /= NTH;
    int co = blk % COUT;
    int b  = blk / COUT;
    int tid = threadIdx.x;
    int tx = tid & 31, ty = tid >> 5;   // ty in [0,8)
    int oh0 = th * TH, ow0 = tw * TW;
    float acc0 = 0, acc1 = 0, acc2 = 0, acc3 = 0;
    const float* xin = in + (size_t)(b * CIN) * (HIN * WIN);
    for (int ci = 0; ci < CIN; ++ci) {
        const float* xc = xin + (size_t)ci * (HIN * WIN);
        for (int i = tid; i < LR * LC; i += TPB) {
            int rr = i / LC, cc = i - rr * LC;
            int gh = 2 * oh0 - 1 + rr, gw = 2 * ow0 - 1 + cc;
            float v = 0.f;
            if ((unsigned)gh < (unsigned)HIN && (unsigned)gw < (unsigned)WIN)
                v = xc[gh * WIN + gw];
            tile[i] = v;
        }
        __syncthreads();
        const float* wc = wgt + ((size_t)co * CIN + ci) * 9;
        float w0 = wc[0], w1 = wc[1], w2 = wc[2],
              w3 = wc[3], w4 = wc[4], w5 = wc[5],
              w6 = wc[6], w7 = wc[7], w8 = wc[8];
        int rbase = 8 * ty, cbase = 2 * tx;
#pragma unroll
        for (int kw = 0; kw < 3; ++kw) {
            float v0 = tile[(rbase + 0) * LC + cbase + kw];
            float v1 = tile[(rbase + 1) * LC + cbase + kw];
            float v2 = tile[(rbase + 2) * LC + cbase + kw];
            float v3 = tile[(rbase + 3) * LC + cbase + kw];
            float v4 = tile[(rbase + 4) * LC + cbase + kw];
            float v5 = tile[(rbase + 5) * LC + cbase + kw];
            float v6 = tile[(rbase + 6) * LC + cbase + kw];
            float v7 = tile[(rbase + 7) * LC + cbase + kw];
            float v8 = tile[(rbase + 8) * LC + cbase + kw];
            float wk0 = (kw == 0 ? w0 : kw == 1 ? w1 : w2);
            float wk1 = (kw == 0 ? w3 : kw == 1 ? w4 : w5);
            float wk2 = (kw == 0 ? w6 : kw == 1 ? w7 : w8);
            acc0 += v0 * wk0 + v1 * wk1 + v2 * wk2;
            acc1 += v2 * wk0 + v3 * wk1 + v4 * wk2;
            acc2 += v4 * wk0 + v5 * wk1 + v6 * wk2;
            acc3 += v6 * wk0 + v7 * wk1 + v8 * wk2;
        }
        __syncthreads();
    }
    float bv = bias[co];
    acc0 += bv; acc1 += bv; acc2 += bv; acc3 += bv;
    int oh = oh0 + ty * 4;
    size_t obase = ((size_t)(b * COUT + co) * HOUT + oh) * WOUT + ow0 + tx;
    outp[obase]            = acc0;
    outp[obase + WOUT]     = acc1;
    outp[obase + 2 * WOUT] = acc2;
    outp[obase + 3 * WOUT] = acc3;
    if (STATS) {
        float ls  = acc0 + acc1 + acc2 + acc3;
        float lss = acc0 * acc0 + acc1 * acc1 + acc2 * acc2 + acc3 * acc3;
        block_stats_atomic(ls, lss, red, &stats[(size_t)b * (COUT / 8) + (co >> 3)]);
    }
}

// ---------------------------------------------------------------------------
// ConvTranspose2d 4x4 stride-2 pad-1: in [16,128,64,64] -> out [16,64,128,128]
// Wt layout [Cin=128, Cout=64, 4, 4].
// y[oh,ow] taps: kh in {p, p+2} with p=(oh+1)&1, ih_a=(oh+1-p)/2 (kh=p),
// ih_b=ih_a-1 (kh=p+2); same for columns. Output tile 64x32 per block;
// thread handles 4 rows x 2 cols (even/odd ow -> compile-time weight indices).
// ---------------------------------------------------------------------------
__global__ __launch_bounds__(TPB) void convt4x4_s2(const float* __restrict__ in,
                                                   const float* __restrict__ wgt,
                                                   const float* __restrict__ bias,
                                                   float* __restrict__ outp,
                                                   float2* __restrict__ stats) {
    constexpr int CIN = 128, COUT = 64, HIN = 64, WIN = 64, HOUT = 128, WOUT = 128;
    constexpr int TH = 64, TW = 32;
    constexpr int NTH = HOUT / TH, NTW = WOUT / TW;   // 2, 4
    constexpr int LR = 34, LC = 18;
    __shared__ float tile[LR * LC];
    __shared__ float red[2 * TPB];
    int blk = blockIdx.x;
    int tw = blk % NTW; blk /= NTW;
    int th = blk % NTH; blk /= NTH;
    int co = blk % COUT;
    int b  = blk / COUT;
    int tid = threadIdx.x;
    int txh = tid & 15, ty = tid >> 4;   // txh: 16 col-pairs, ty: 16 row-quads
    int oh0 = th * TH, ow0 = tw * TW;
    int ihb = oh0 / 2 - 1, iwb = ow0 / 2 - 1;
    float acc[4][2] = {};
    const float* xin = in + (size_t)(b * CIN) * (HIN * WIN);
    for (int ci = 0; ci < CIN; ++ci) {
        const float* xc = xin + (size_t)ci * (HIN * WIN);
        for (int i = tid; i < LR * LC; i += TPB) {
            int rr = i / LC, cc = i - rr * LC;
            int gh = ihb + rr, gw = iwb + cc;
            float v = 0.f;
            if ((unsigned)gh < 64u && (unsigned)gw < 64u)
                v = xc[gh * 64 + gw];
            tile[i] = v;
        }
        __syncthreads();
        const float* wc = wgt + (size_t)(ci * COUT + co) * 16;
        float wv[16];
#pragma unroll
        for (int i = 0; i < 16; ++i) wv[i] = wc[i];
#pragma unroll
        for (int r = 0; r < 4; ++r) {
            const int p  = (r + 1) & 1;               // kh parity class
            int ra = ty * 2 + 1 + ((r + 1) >> 1);     // row for kh=p
            int rb = ra - 1;                          // row for kh=p+2
            float xa0 = tile[ra * LC + txh];
            float xa1 = tile[ra * LC + txh + 1];
            float xa2 = tile[ra * LC + txh + 2];
            float xb0 = tile[rb * LC + txh];
            float xb1 = tile[rb * LC + txh + 1];
            float xb2 = tile[rb * LC + txh + 2];
            // even ow (q=1): x[ca]=x[txh+1] w[kh][1]; x[cb]=x[txh] w[kh][3]
            acc[r][0] += xa1 * wv[p * 4 + 1] + xa0 * wv[p * 4 + 3]
                       + xb1 * wv[(p + 2) * 4 + 1] + xb0 * wv[(p + 2) * 4 + 3];
            // odd ow (q=0): x[ca]=x[txh+2] w[kh][0]; x[cb]=x[txh+1] w[kh][2]
            acc[r][1] += xa2 * wv[p * 4 + 0] + xa1 * wv[p * 4 + 2]
                       + xb2 * wv[(p + 2) * 4 + 0] + xb1 * wv[(p + 2) * 4 + 2];
        }
        __syncthreads();
    }
    float bv = bias[co];
    float ls = 0, lss = 0;
#pragma unroll
    for (int r = 0; r < 4; ++r) {
        acc[r][0] += bv; acc[r][1] += bv;
        ls += acc[r][0] + acc[r][1];
        lss += acc[r][0] * acc[r][0] + acc[r][1] * acc[r][1];
        int oh = oh0 + ty * 4 + r;
        float2* o = (float2*)(outp + ((size_t)(b * COUT + co) * HOUT + oh) * WOUT + ow0) + txh;
        *o = make_float2(acc[r][0], acc[r][1]);
    }
    block_stats_atomic(ls, lss, red, &stats[(size_t)b * (COUT / 8) + (co >> 3)]);
}

// ---------------------------------------------------------------------------
// GroupNorm (8 channels per group, all stages) + ReLU, in place.
// ---------------------------------------------------------------------------
template<int C, int HW, int GN>
__global__ __launch_bounds__(TPB) void gn_relu(float* __restrict__ data,
                                               const float2* __restrict__ stats,
                                               const float* __restrict__ gamma,
                                               const float* __restrict__ beta,
                                               float invCount) {
    int idx = blockIdx.x * TPB + threadIdx.x;
    int c = (idx / HW) % C;
    int b = idx / (HW * C);
    float2 st = stats[b * GN + (c >> 3)];
    float mean = st.x * invCount;
    float var  = st.y * invCount - mean * mean;
    float xv = data[idx];
    float y = (xv - mean) * rsqrtf(var + 1e-5f) * gamma[c] + beta[c];
    data[idx] = fmaxf(y, 0.f);
}

// ---------------------------------------------------------------------------
extern "C" void kernel_launch(void* const* d_in, const int* in_sizes, int n_in,
                              void* d_out, int out_size, void* d_ws, size_t ws_size,
                              hipStream_t stream) {
    const float* x   = (const float*)d_in[0];
    const float* Kd  = (const float*)d_in[1];
    const float* Kr  = (const float*)d_in[2];
    const float* W1  = (const float*)d_in[3];  const float* b1  = (const float*)d_in[4];
    const float* g1  = (const float*)d_in[5];  const float* be1 = (const float*)d_in[6];
    const float* W2  = (const float*)d_in[7];  const float* b2  = (const float*)d_in[8];
    const float* g2  = (const float*)d_in[9];  const float* be2 = (const float*)d_in[10];
    const float* W3  = (const float*)d_in[11]; const float* b3  = (const float*)d_in[12];
    const float* g3  = (const float*)d_in[13]; const float* be3 = (const float*)d_in[14];
    const float* W4  = (const float*)d_in[15]; const float* b4  = (const float*)d_in[16];
    const float* g4  = (const float*)d_in[17]; const float* be4 = (const float*)d_in[18];
    const float* Wt  = (const float*)d_in[19]; const float* bt  = (const float*)d_in[20];
    const float* g5  = (const float*)d_in[21]; const float* be5 = (const float*)d_in[22];
    const float* W6  = (const float*)d_in[23]; const float* b6  = (const float*)d_in[24];

    float*  P     = (float*)d_ws;                  // 16,777,216 floats (64 MB+)
    float*  Q     = P + 16777216;                  //  8,388,608 floats
    float2* stats = (float2*)(Q + 8388608);        //  1280 float2 (10 KB)
    float*  out   = (float*)d_out;

    hipMemsetAsync(stats, 0, 1280 * sizeof(float2), stream);

    // DWT: x -> Q [16,32,128,128]
    dwt_kernel<<<8192, TPB, 0, stream>>>(x, Kd, Q);

    // conv1 32->64 @128: Q -> P, stats[0..128)
    conv3x3_s1<32, 64, 128, 128, true><<<16 * 64 * 2 * 8, TPB, 0, stream>>>(Q, W1, b1, P, stats + 0);
    gn_relu<64, 16384, 8><<<65536, TPB, 0, stream>>>(P, stats + 0, g1, be1, 1.f / 131072.f);

    // conv2 64->128 stride2: P -> Q [16,128,64,64], stats[128..384)
    conv3x3_s2<64, 128, 128, 128, true><<<16 * 128 * 1 * 2 * 2, TPB, 0, stream>>>(P, W2, b2, Q, stats + 128);
    gn_relu<128, 4096, 16><<<32768, TPB, 0, stream>>>(Q, stats + 128, g2, be2, 1.f / 32768.f);

    // conv3 128->256 @64: Q -> P, stats[384..896)
    conv3x3_s1<128, 256, 64, 64, true><<<16 * 256 * 1 * 4, TPB, 0, stream>>>(Q, W3, b3, P, stats + 384);
    gn_relu<256, 4096, 32><<<65536, TPB, 0, stream>>>(P, stats + 384, g3, be3, 1.f / 32768.f);

    // conv4 256->128 @64: P -> Q, stats[896..1152)
    conv3x3_s1<256, 128, 64, 64, true><<<16 * 128 * 1 * 4, TPB, 0, stream>>>(P, W4, b4, Q, stats + 896);
    gn_relu<128, 4096, 16><<<32768, TPB, 0, stream>>>(Q, stats + 896, g4, be4, 1.f / 32768.f);

    // convT 128->64 x2: Q -> P [16,64,128,128], stats[1152..1280)
    convt4x4_s2<<<16 * 64 * 2 * 4, TPB, 0, stream>>>(Q, Wt, bt, P, stats + 1152);
    gn_relu<64, 16384, 8><<<65536, TPB, 0, stream>>>(P, stats + 1152, g5, be5, 1.f / 131072.f);

    // conv6 64->16 @128: P -> Q [16,16,128,128], no GN
    conv3x3_s1<64, 16, 128, 128, false><<<16 * 16 * 2 * 8, TPB, 0, stream>>>(P, W6, b6, Q, nullptr);

    // IDWT: Q -> out [16,4,256,256]
    idwt_kernel<<<4096, TPB, 0, stream>>>(Q, Kr, out);
}

// Round 2
// 749.787 us; speedup vs baseline: 10.6043x; 10.6043x over previous
//
#include <hip/hip_runtime.h>

typedef unsigned short ushort_t;
typedef unsigned int uint_t;
typedef __attribute__((ext_vector_type(8))) short short8;
typedef __attribute__((ext_vector_type(4))) float f32x4;

__device__ __forceinline__ ushort_t f2bf(float f) {
    uint_t u = __float_as_uint(f);
    u = (u + 0x7FFFu + ((u >> 16) & 1u)) >> 16;
    return (ushort_t)u;
}
__device__ __forceinline__ float bf2f(ushort_t h) {
    return __uint_as_float(((uint_t)h) << 16);
}

__device__ __forceinline__ void red_stats(float& s, float& ss) {
    s += __shfl_xor(s, 16); ss += __shfl_xor(ss, 16);
    s += __shfl_xor(s, 32); ss += __shfl_xor(ss, 32);
    s += __shfl_xor(s, 1);  ss += __shfl_xor(ss, 1);
    s += __shfl_xor(s, 2);  ss += __shfl_xor(ss, 2);
    s += __shfl_xor(s, 4);  ss += __shfl_xor(ss, 4);
}

// ---------------------------------------------------------------------------
// Weight pack (3x3 convs): W [COUT, CIN, 3, 3] fp32 ->
// wp[((cib*9 + tap)*COUT + co)*32 + kk] bf16, ci = cib*32+kk, tap = kh*3+kw
// ---------------------------------------------------------------------------
template<int CIN, int COUT>
__global__ __launch_bounds__(256) void pack_w(const float* __restrict__ W,
                                              ushort_t* __restrict__ wp) {
    int idx = blockIdx.x * 256 + threadIdx.x;
    if (idx >= CIN * COUT * 9) return;
    int kk = idx & 31;
    int t = idx >> 5;
    int co = t % COUT; t /= COUT;
    int tap = t % 9;
    int cib = t / 9;
    int ci = cib * 32 + kk;
    wp[idx] = f2bf(W[(co * CIN + ci) * 9 + tap]);
}

// Weight pack convT: Wt [128, 64, 4, 4] ->
// wp[(((ph*4 + cib)*4 + tap)*64 + co)*32 + kk], tap = rs*2+cs, ph = eh*2+ew
__global__ __launch_bounds__(256) void pack_wt(const float* __restrict__ Wt,
                                               ushort_t* __restrict__ wp) {
    int idx = blockIdx.x * 256 + threadIdx.x;
    if (idx >= 131072) return;
    int kk = idx & 31;
    int t = idx >> 5;
    int co = t & 63; t >>= 6;
    int tap = t & 3; t >>= 2;
    int cib = t & 3;
    int ph = t >> 2;
    int rs = tap >> 1, cs = tap & 1;
    int eh = ph >> 1, ew = ph & 1;
    int kh = eh ? (rs ? 0 : 2) : (rs ? 1 : 3);
    int kw = ew ? (cs ? 0 : 2) : (cs ? 1 : 3);
    int ci = cib * 32 + kk;
    wp[idx] = f2bf(Wt[((ci * 64 + co) * 4 + kh) * 4 + kw]);
}

// ---------------------------------------------------------------------------
// DWT: x NCHW fp32 [16,8,256,256] -> NHWC bf16 [16,128,128,32], ch = 4*ci+band
// ---------------------------------------------------------------------------
__global__ __launch_bounds__(256) void dwt_nhwc(const float* __restrict__ x,
                                                const float* __restrict__ Kd,
                                                ushort_t* __restrict__ out) {
    int idx = blockIdx.x * 256 + threadIdx.x;    // b*16384 + h*128 + w
    int w = idx & 127, h = (idx >> 7) & 127, b = idx >> 14;
    float k[16];
#pragma unroll
    for (int i = 0; i < 16; ++i) k[i] = Kd[i];
    const float* xb = x + (size_t)b * 8 * 65536;
    uint_t uu[16];
#pragma unroll
    for (int ci = 0; ci < 8; ++ci) {
        const float* p = xb + ci * 65536 + (2 * h) * 256 + 2 * w;
        float2 r0 = *(const float2*)p;
        float2 r1 = *(const float2*)(p + 256);
        ushort_t o[4];
#pragma unroll
        for (int sb = 0; sb < 4; ++sb) {
            float v = r0.x * k[sb*4] + r0.y * k[sb*4+1] + r1.x * k[sb*4+2] + r1.y * k[sb*4+3];
            o[sb] = f2bf(v);
        }
        uu[ci*2]   = (uint_t)o[0] | ((uint_t)o[1] << 16);
        uu[ci*2+1] = (uint_t)o[2] | ((uint_t)o[3] << 16);
    }
    uint4* dst = (uint4*)(out + (size_t)idx * 32);
    dst[0] = make_uint4(uu[0], uu[1], uu[2], uu[3]);
    dst[1] = make_uint4(uu[4], uu[5], uu[6], uu[7]);
    dst[2] = make_uint4(uu[8], uu[9], uu[10], uu[11]);
    dst[3] = make_uint4(uu[12], uu[13], uu[14], uu[15]);
}

// ---------------------------------------------------------------------------
// IDWT: in NHWC fp32 [16,128,128,16] -> out NCHW fp32 [16,4,256,256]
// ---------------------------------------------------------------------------
__global__ __launch_bounds__(256) void idwt_nhwc(const float* __restrict__ cin,
                                                 const float* __restrict__ Kr,
                                                 float* __restrict__ out) {
    int idx = blockIdx.x * 256 + threadIdx.x;    // b*16384 + h*128 + w
    int w = idx & 127, h = (idx >> 7) & 127, b = idx >> 14;
    float k[16];
#pragma unroll
    for (int i = 0; i < 16; ++i) k[i] = Kr[i];
    const float* p = cin + (size_t)idx * 16;
#pragma unroll
    for (int c = 0; c < 4; ++c) {
        float y00 = 0, y01 = 0, y10 = 0, y11 = 0;
#pragma unroll
        for (int sb = 0; sb < 4; ++sb) {
            float v = p[c * 4 + sb];
            y00 += v * k[sb*4];   y01 += v * k[sb*4+1];
            y10 += v * k[sb*4+2]; y11 += v * k[sb*4+3];
        }
        float* ob = out + ((size_t)(b * 4 + c) * 256 + 2 * h) * 256 + 2 * w;
        *(float2*)ob = make_float2(y00, y01);
        *(float2*)(ob + 256) = make_float2(y10, y11);
    }
}

// ---------------------------------------------------------------------------
// Implicit-GEMM 3x3 conv, NHWC bf16 in/out, MFMA 16x16x32 bf16.
// Block = 256 thr (4 waves). Block tile: MT = NR*64 px x NT couts.
// Wave: 16*NR px x NT couts -> acc[NR][NT/16] frags.
// ---------------------------------------------------------------------------
template<int CIN, int COUT, int HOUT, int WOUT, int S, int NR, bool STATS, bool OUTF32>
__global__ __launch_bounds__(256) void conv_mfma(const ushort_t* __restrict__ in,
                                                 const ushort_t* __restrict__ wp,
                                                 const float* __restrict__ bias,
                                                 void* __restrict__ outp,
                                                 float2* __restrict__ stats) {
    constexpr int NT = (COUT < 64) ? COUT : 64;
    constexpr int NF = NT / 16;
    constexpr int NCB = CIN / 32;
    constexpr int HIN = HOUT * S, WIN = WOUT * S;
    constexpr int IW = 64 * S + 2;
    constexpr int NRI = (NR - 1) * S + 3;
    constexpr int MCH = 16 * NR;
    constexpr int NB = COUT / NT, NW = WOUT / 64, NH = HOUT / NR;

    __shared__ ushort_t lA[NRI * IW * 32];
    __shared__ ushort_t lB[9 * NT * 32];

    int bid = blockIdx.x;
    int nb = bid % NB; bid /= NB;
    int wt = bid % NW; bid /= NW;
    int ht = bid % NH;
    int b  = bid / NH;
    int h0 = ht * NR, w0 = wt * 64, n0 = nb * NT;
    int tid = threadIdx.x;
    int lane = tid & 63, wid = tid >> 6;
    int nl = lane & 15, ql = (lane >> 4) * 8;
    int M0 = wid * MCH;

    int rr[NR], cl[NR];
#pragma unroll
    for (int mf = 0; mf < NR; ++mf) {
        int m = M0 + mf * 16;
        rr[mf] = m >> 6;
        cl[mf] = (m & 63) + nl;
    }

    f32x4 acc[NR][NF];
#pragma unroll
    for (int mf = 0; mf < NR; ++mf)
#pragma unroll
        for (int nf = 0; nf < NF; ++nf)
            acc[mf][nf] = (f32x4){0.f, 0.f, 0.f, 0.f};

    const ushort_t* ibase = in + (size_t)b * HIN * WIN * CIN;

    for (int cib = 0; cib < NCB; ++cib) {
        // stage A: NRI rows x IW px x 32 ch
        for (int i = tid; i < NRI * IW * 4; i += 256) {
            int tr = i / (IW * 4), rem = i - tr * (IW * 4);
            int p = rem >> 2, part = rem & 3;
            int ih = h0 * S - 1 + tr;
            int iw = w0 * S - 1 + p;
            uint4 v = make_uint4(0, 0, 0, 0);
            if ((unsigned)ih < (unsigned)HIN && (unsigned)iw < (unsigned)WIN)
                v = *(const uint4*)(ibase + ((size_t)ih * WIN + iw) * CIN + cib * 32 + part * 8);
            *(uint4*)&lA[(tr * IW + p) * 32 + part * 8] = v;
        }
        // stage B: 9 taps x NT co x 32 k
        const ushort_t* wb = wp + (size_t)cib * 9 * COUT * 32;
        for (int i = tid; i < 9 * NT * 4; i += 256) {
            int tap = i / (NT * 4), rem = i - tap * (NT * 4);
            int co = rem >> 2, part = rem & 3;
            *(uint4*)&lB[(tap * NT + co) * 32 + part * 8] =
                *(const uint4*)(wb + ((size_t)tap * COUT + n0 + co) * 32 + part * 8);
        }
        __syncthreads();

#pragma unroll
        for (int tap = 0; tap < 9; ++tap) {
            const int kh = tap / 3, kw = tap % 3;
            short8 af[NR];
#pragma unroll
            for (int mf = 0; mf < NR; ++mf)
                af[mf] = *(const short8*)&lA[((rr[mf] * S + kh) * IW + cl[mf] * S + kw) * 32 + ql];
            short8 bf[NF];
#pragma unroll
            for (int nf = 0; nf < NF; ++nf)
                bf[nf] = *(const short8*)&lB[(tap * NT + nf * 16 + nl) * 32 + ql];
#pragma unroll
            for (int mf = 0; mf < NR; ++mf)
#pragma unroll
                for (int nf = 0; nf < NF; ++nf)
                    acc[mf][nf] = __builtin_amdgcn_mfma_f32_16x16x32_bf16(
                        af[mf], bf[nf], acc[mf][nf], 0, 0, 0);
        }
        __syncthreads();
    }

    // epilogue: bias, store, fused GN stats
    int quad = lane >> 4;
    float bs[NF];
#pragma unroll
    for (int nf = 0; nf < NF; ++nf) bs[nf] = bias[n0 + nf * 16 + nl];

#pragma unroll
    for (int nf = 0; nf < NF; ++nf) {
        float s = 0.f, ss = 0.f;
#pragma unroll
        for (int mf = 0; mf < NR; ++mf) {
#pragma unroll
            for (int rg = 0; rg < 4; ++rg) {
                int m = M0 + mf * 16 + quad * 4 + rg;
                int r = m >> 6, c = m & 63;
                float v = acc[mf][nf][rg] + bs[nf];
                size_t oa = (((size_t)b * HOUT + h0 + r) * WOUT + w0 + c) * COUT
                          + n0 + nf * 16 + nl;
                if (OUTF32) ((float*)outp)[oa] = v;
                else        ((ushort_t*)outp)[oa] = f2bf(v);
                s += v; ss += v * v;
            }
        }
        if (STATS) {
            red_stats(s, ss);
            if (quad == 0 && (nl & 7) == 0) {
                int g = (n0 + nf * 16 + nl) >> 3;
                atomicAdd(&stats[(size_t)b * (COUT / 8) + g].x, s);
                atomicAdd(&stats[(size_t)b * (COUT / 8) + g].y, ss);
            }
        }
    }
}

// ---------------------------------------------------------------------------
// ConvTranspose 4x4 s2 p1 as 4 phase convs (2x2 taps each).
// in NHWC bf16 [16,64,64,128] -> out NHWC bf16 [16,128,128,64]
// ---------------------------------------------------------------------------
__global__ __launch_bounds__(256) void convt_mfma(const ushort_t* __restrict__ in,
                                                  const ushort_t* __restrict__ wp,
                                                  const float* __restrict__ bias,
                                                  ushort_t* __restrict__ outp,
                                                  float2* __restrict__ stats) {
    constexpr int CIN = 128, COUT = 64, NT = 64, NF = 4, NCB = 4;
    constexpr int IW = 66, NRI = 5, NR = 4;
    __shared__ ushort_t lA[NRI * IW * 32];
    __shared__ ushort_t lB[4 * NT * 32];

    int bid = blockIdx.x;
    int ht = bid & 15; bid >>= 4;
    int ph = bid & 3;
    int b  = bid >> 2;
    int eh = ph >> 1, ew = ph & 1;
    int ho0 = ht * 4;
    int tid = threadIdx.x;
    int lane = tid & 63, wid = tid >> 6;
    int nl = lane & 15, ql = (lane >> 4) * 8;

    f32x4 acc[NR][NF];
#pragma unroll
    for (int mf = 0; mf < NR; ++mf)
#pragma unroll
        for (int nf = 0; nf < NF; ++nf)
            acc[mf][nf] = (f32x4){0.f, 0.f, 0.f, 0.f};

    const ushort_t* ibase = in + (size_t)b * 64 * 64 * CIN;

    for (int cib = 0; cib < NCB; ++cib) {
        for (int i = tid; i < NRI * IW * 4; i += 256) {
            int tr = i / (IW * 4), rem = i - tr * (IW * 4);
            int p = rem >> 2, part = rem & 3;
            int ih = ho0 + tr - (1 - eh);
            int iw = p - 1;
            uint4 v = make_uint4(0, 0, 0, 0);
            if ((unsigned)ih < 64u && (unsigned)iw < 64u)
                v = *(const uint4*)(ibase + ((size_t)ih * 64 + iw) * CIN + cib * 32 + part * 8);
            *(uint4*)&lA[(tr * IW + p) * 32 + part * 8] = v;
        }
        const ushort_t* wb = wp + ((size_t)ph * 4 + cib) * 4 * COUT * 32;
        for (int i = tid; i < 4 * NT * 4; i += 256) {
            int tap = i / (NT * 4), rem = i - tap * (NT * 4);
            int co = rem >> 2, part = rem & 3;
            *(uint4*)&lB[(tap * NT + co) * 32 + part * 8] =
                *(const uint4*)(wb + ((size_t)tap * COUT + co) * 32 + part * 8);
        }
        __syncthreads();

#pragma unroll
        for (int tap = 0; tap < 4; ++tap) {
            const int rs = tap >> 1, cs = tap & 1;
            short8 af[NR];
#pragma unroll
            for (int mf = 0; mf < NR; ++mf)
                af[mf] = *(const short8*)&lA[((wid + rs) * IW + mf * 16 + nl + cs + ew) * 32 + ql];
            short8 bf[NF];
#pragma unroll
            for (int nf = 0; nf < NF; ++nf)
                bf[nf] = *(const short8*)&lB[(tap * NT + nf * 16 + nl) * 32 + ql];
#pragma unroll
            for (int mf = 0; mf < NR; ++mf)
#pragma unroll
                for (int nf = 0; nf < NF; ++nf)
                    acc[mf][nf] = __builtin_amdgcn_mfma_f32_16x16x32_bf16(
                        af[mf], bf[nf], acc[mf][nf], 0, 0, 0);
        }
        __syncthreads();
    }

    int quad = lane >> 4;
    float bs[NF];
#pragma unroll
    for (int nf = 0; nf < NF; ++nf) bs[nf] = bias[nf * 16 + nl];
    int oh = 2 * (ho0 + wid) + eh;
#pragma unroll
    for (int nf = 0; nf < NF; ++nf) {
        float s = 0.f, ss = 0.f;
#pragma unroll
        for (int mf = 0; mf < NR; ++mf) {
#pragma unroll
            for (int rg = 0; rg < 4; ++rg) {
                int wo = mf * 16 + quad * 4 + rg;
                float v = acc[mf][nf][rg] + bs[nf];
                size_t oa = (((size_t)b * 128 + oh) * 128 + 2 * wo + ew) * 64 + nf * 16 + nl;
                outp[oa] = f2bf(v);
                s += v; ss += v * v;
            }
        }
        red_stats(s, ss);
        if (quad == 0 && (nl & 7) == 0) {
            int g = (nf * 16 + nl) >> 3;
            atomicAdd(&stats[(size_t)b * 8 + g].x, s);
            atomicAdd(&stats[(size_t)b * 8 + g].y, ss);
        }
    }
}

// ---------------------------------------------------------------------------
// GroupNorm(8ch/group) + ReLU over NHWC bf16, 8 channels per thread.
// ---------------------------------------------------------------------------
template<int C, int HW>
__global__ __launch_bounds__(256) void gn_relu(ushort_t* __restrict__ data,
                                               const float2* __restrict__ stats,
                                               const float* __restrict__ gamma,
                                               const float* __restrict__ beta,
                                               float invC) {
    int idx = blockIdx.x * 256 + threadIdx.x;
    int e8 = idx * 8;
    int c0 = e8 & (C - 1);
    int b = e8 / (HW * C);
    float2 st = stats[(size_t)b * (C / 8) + (c0 >> 3)];
    float mean = st.x * invC;
    float var = st.y * invC - mean * mean;
    float rstd = rsqrtf(var + 1e-5f);
    uint4 v = ((const uint4*)data)[idx];
    uint_t u[4] = {v.x, v.y, v.z, v.w};
    uint_t r[4];
#pragma unroll
    for (int p = 0; p < 4; ++p) {
        int c = c0 + p * 2;
        float f0 = bf2f((ushort_t)(u[p] & 0xffffu));
        float f1 = bf2f((ushort_t)(u[p] >> 16));
        f0 = fmaxf((f0 - mean) * rstd * gamma[c] + beta[c], 0.f);
        f1 = fmaxf((f1 - mean) * rstd * gamma[c + 1] + beta[c + 1], 0.f);
        r[p] = (uint_t)f2bf(f0) | ((uint_t)f2bf(f1) << 16);
    }
    ((uint4*)data)[idx] = make_uint4(r[0], r[1], r[2], r[3]);
}

// ---------------------------------------------------------------------------
extern "C" void kernel_launch(void* const* d_in, const int* in_sizes, int n_in,
                              void* d_out, int out_size, void* d_ws, size_t ws_size,
                              hipStream_t stream) {
    const float* x   = (const float*)d_in[0];
    const float* Kd  = (const float*)d_in[1];
    const float* Kr  = (const float*)d_in[2];
    const float* W1  = (const float*)d_in[3];  const float* b1  = (const float*)d_in[4];
    const float* g1  = (const float*)d_in[5];  const float* be1 = (const float*)d_in[6];
    const float* W2  = (const float*)d_in[7];  const float* b2  = (const float*)d_in[8];
    const float* g2  = (const float*)d_in[9];  const float* be2 = (const float*)d_in[10];
    const float* W3  = (const float*)d_in[11]; const float* b3  = (const float*)d_in[12];
    const float* g3  = (const float*)d_in[13]; const float* be3 = (const float*)d_in[14];
    const float* W4  = (const float*)d_in[15]; const float* b4  = (const float*)d_in[16];
    const float* g4  = (const float*)d_in[17]; const float* be4 = (const float*)d_in[18];
    const float* Wt  = (const float*)d_in[19]; const float* bt  = (const float*)d_in[20];
    const float* g5  = (const float*)d_in[21]; const float* be5 = (const float*)d_in[22];
    const float* W6  = (const float*)d_in[23]; const float* b6  = (const float*)d_in[24];

    ushort_t* U  = (ushort_t*)d_ws;           // 8,388,608 elems (A0/A2/A4/A6)
    ushort_t* V  = U + 8388608;               // 16,777,216 elems (A1/A3/A5)
    ushort_t* WP = V + 16777216;
    ushort_t* wp1 = WP;
    ushort_t* wp2 = wp1 + 18432;
    ushort_t* wp3 = wp2 + 73728;
    ushort_t* wp4 = wp3 + 294912;
    ushort_t* wpt = wp4 + 294912;
    ushort_t* wp6 = wpt + 131072;
    float2* stats = (float2*)(wp6 + 9216);    // 1280 float2
    float* out = (float*)d_out;

    hipMemsetAsync(stats, 0, 1280 * sizeof(float2), stream);

    // pack weights (bf16, [cib][tap][co][32k])
    pack_w<32, 64>  <<<72,   256, 0, stream>>>(W1, wp1);
    pack_w<64, 128> <<<288,  256, 0, stream>>>(W2, wp2);
    pack_w<128, 256><<<1152, 256, 0, stream>>>(W3, wp3);
    pack_w<256, 128><<<1152, 256, 0, stream>>>(W4, wp4);
    pack_wt         <<<512,  256, 0, stream>>>(Wt, wpt);
    pack_w<64, 16>  <<<36,   256, 0, stream>>>(W6, wp6);

    // DWT: x -> U (A0 [16,128,128,32] bf16)
    dwt_nhwc<<<1024, 256, 0, stream>>>(x, Kd, U);

    // conv1 32->64 @128x128: U -> V
    conv_mfma<32, 64, 128, 128, 1, 4, true, false>
        <<<16 * 32 * 2 * 1, 256, 0, stream>>>(U, wp1, b1, V, stats + 0);
    gn_relu<64, 16384><<<8192, 256, 0, stream>>>(V, stats + 0, g1, be1, 1.f / 131072.f);

    // conv2 64->128 s2: V -> U (A2 [16,64,64,128])
    conv_mfma<64, 128, 64, 64, 2, 1, true, false>
        <<<16 * 64 * 1 * 2, 256, 0, stream>>>(V, wp2, b2, U, stats + 128);
    gn_relu<128, 4096><<<4096, 256, 0, stream>>>(U, stats + 128, g2, be2, 1.f / 32768.f);

    // conv3 128->256 @64x64: U -> V
    conv_mfma<128, 256, 64, 64, 1, 4, true, false>
        <<<16 * 16 * 1 * 4, 256, 0, stream>>>(U, wp3, b3, V, stats + 384);
    gn_relu<256, 4096><<<8192, 256, 0, stream>>>(V, stats + 384, g3, be3, 1.f / 32768.f);

    // conv4 256->128 @64x64: V -> U (A4)
    conv_mfma<256, 128, 64, 64, 1, 4, true, false>
        <<<16 * 16 * 1 * 2, 256, 0, stream>>>(V, wp4, b4, U, stats + 896);
    gn_relu<128, 4096><<<4096, 256, 0, stream>>>(U, stats + 896, g4, be4, 1.f / 32768.f);

    // convT 128->64 x2: U -> V (A5 [16,128,128,64])
    convt_mfma<<<16 * 4 * 16, 256, 0, stream>>>(U, wpt, bt, V, stats + 1152);
    gn_relu<64, 16384><<<8192, 256, 0, stream>>>(V, stats + 1152, g5, be5, 1.f / 131072.f);

    // conv6 64->16 @128x128: V -> U (A6 fp32 NHWC [16,128,128,16])
    conv_mfma<64, 16, 128, 128, 1, 4, false, true>
        <<<16 * 32 * 2 * 1, 256, 0, stream>>>(V, wp6, b6, U, nullptr);

    // IDWT: U -> out
    idwt_nhwc<<<1024, 256, 0, stream>>>((const float*)U, Kr, out);
}

// Round 3
// 529.481 us; speedup vs baseline: 15.0166x; 1.4161x over previous
//
#include <hip/hip_runtime.h>

typedef unsigned short ushort_t;
typedef unsigned int uint_t;
typedef __attribute__((ext_vector_type(8))) short short8;
typedef __attribute__((ext_vector_type(4))) float f32x4;

#define PAD 40   // LDS elems per pixel/co row (32 data + 8 pad) -> bank stride 20, 2-way free

__device__ __forceinline__ ushort_t f2bf(float f) {
    uint_t u = __float_as_uint(f);
    u = (u + 0x7FFFu + ((u >> 16) & 1u)) >> 16;
    return (ushort_t)u;
}
__device__ __forceinline__ float bf2f(ushort_t h) {
    return __uint_as_float(((uint_t)h) << 16);
}

__device__ __forceinline__ void red_stats(float& s, float& ss) {
    s += __shfl_xor(s, 16); ss += __shfl_xor(ss, 16);
    s += __shfl_xor(s, 32); ss += __shfl_xor(ss, 32);
    s += __shfl_xor(s, 1);  ss += __shfl_xor(ss, 1);
    s += __shfl_xor(s, 2);  ss += __shfl_xor(ss, 2);
    s += __shfl_xor(s, 4);  ss += __shfl_xor(ss, 4);
}

// ---------------------------------------------------------------------------
// Weight packing (merged into one kernel)
// ---------------------------------------------------------------------------
template<int CIN, int COUT>
__device__ __forceinline__ void pack3(const float* __restrict__ W, ushort_t* __restrict__ wp, int idx) {
    int kk = idx & 31;
    int t = idx >> 5;
    int co = t % COUT; t /= COUT;
    int tap = t % 9;
    int cib = t / 9;
    wp[idx] = f2bf(W[(co * CIN + cib * 32 + kk) * 9 + tap]);
}

// conv2 parity pack: wp[cib(8)][tap(4)][co(128)][kk(32)]
// cib: p=cib>>2, q=(cib>>1)&1, chalf=cib&1; tap: kh'=tap>>1, kw'=tap&1
// kh=2kh'+p-1, kw=2kw'+q-1 (out-of-range -> 0)
__device__ __forceinline__ void pack2p(const float* __restrict__ W2, ushort_t* __restrict__ wp, int idx) {
    int kk = idx & 31;
    int co = (idx >> 5) & 127;
    int tap = (idx >> 12) & 3;
    int cib = idx >> 14;
    int p = cib >> 2, q = (cib >> 1) & 1, chalf = cib & 1;
    int kh = 2 * (tap >> 1) + p - 1;
    int kw = 2 * (tap & 1) + q - 1;
    float v = 0.f;
    if (kh >= 0 && kh < 3 && kw >= 0 && kw < 3)
        v = W2[(co * 64 + chalf * 32 + kk) * 9 + kh * 3 + kw];
    wp[idx] = f2bf(v);
}

// convT pack: wp[(((ph*4+cib)*4+tap)*64+co)*32+kk]
__device__ __forceinline__ void packt(const float* __restrict__ Wt, ushort_t* __restrict__ wp, int idx) {
    int kk = idx & 31;
    int t = idx >> 5;
    int co = t & 63; t >>= 6;
    int tap = t & 3; t >>= 2;
    int cib = t & 3;
    int ph = t >> 2;
    int rs = tap >> 1, cs = tap & 1;
    int eh = ph >> 1, ew = ph & 1;
    int kh = eh ? (rs ? 0 : 2) : (rs ? 1 : 3);
    int kw = ew ? (cs ? 0 : 2) : (cs ? 1 : 3);
    wp[idx] = f2bf(Wt[((cib * 32 + kk) * 64 + co) * 16 + kh * 4 + kw]);
}

__global__ __launch_bounds__(256) void pack_all(const float* __restrict__ W1,
                                                const float* __restrict__ W2,
                                                const float* __restrict__ W3,
                                                const float* __restrict__ W4,
                                                const float* __restrict__ Wt,
                                                const float* __restrict__ W6,
                                                ushort_t* __restrict__ WP) {
    int idx = blockIdx.x * 256 + threadIdx.x;
    // offsets: wp1 0, wp2 18432, wp3 149504, wp4 444416, wpt 739328, wp6 870400, end 879616
    if (idx < 18432)        pack3<32, 64>(W1, WP, idx);
    else if (idx < 149504)  pack2p(W2, WP + 18432, idx - 18432);
    else if (idx < 444416)  pack3<128, 256>(W3, WP + 149504, idx - 149504);
    else if (idx < 739328)  pack3<256, 128>(W4, WP + 444416, idx - 444416);
    else if (idx < 870400)  packt(Wt, WP + 739328, idx - 739328);
    else if (idx < 879616)  pack3<64, 16>(W6, WP + 870400, idx - 870400);
}

// ---------------------------------------------------------------------------
// DWT: x NCHW fp32 [16,8,256,256] -> NHWC bf16 [16,128,128,32], ch = 4*ci+band
// ---------------------------------------------------------------------------
__global__ __launch_bounds__(256) void dwt_nhwc(const float* __restrict__ x,
                                                const float* __restrict__ Kd,
                                                ushort_t* __restrict__ out) {
    int idx = blockIdx.x * 256 + threadIdx.x;
    int w = idx & 127, h = (idx >> 7) & 127, b = idx >> 14;
    float k[16];
#pragma unroll
    for (int i = 0; i < 16; ++i) k[i] = Kd[i];
    const float* xb = x + (size_t)b * 8 * 65536;
    uint_t uu[16];
#pragma unroll
    for (int ci = 0; ci < 8; ++ci) {
        const float* p = xb + ci * 65536 + (2 * h) * 256 + 2 * w;
        float2 r0 = *(const float2*)p;
        float2 r1 = *(const float2*)(p + 256);
        ushort_t o[4];
#pragma unroll
        for (int sb = 0; sb < 4; ++sb) {
            float v = r0.x * k[sb*4] + r0.y * k[sb*4+1] + r1.x * k[sb*4+2] + r1.y * k[sb*4+3];
            o[sb] = f2bf(v);
        }
        uu[ci*2]   = (uint_t)o[0] | ((uint_t)o[1] << 16);
        uu[ci*2+1] = (uint_t)o[2] | ((uint_t)o[3] << 16);
    }
    uint4* dst = (uint4*)(out + (size_t)idx * 32);
    dst[0] = make_uint4(uu[0], uu[1], uu[2], uu[3]);
    dst[1] = make_uint4(uu[4], uu[5], uu[6], uu[7]);
    dst[2] = make_uint4(uu[8], uu[9], uu[10], uu[11]);
    dst[3] = make_uint4(uu[12], uu[13], uu[14], uu[15]);
}

// ---------------------------------------------------------------------------
// IDWT: in NHWC fp32 [16,128,128,16] -> out NCHW fp32 [16,4,256,256]
// ---------------------------------------------------------------------------
__global__ __launch_bounds__(256) void idwt_nhwc(const float* __restrict__ cin,
                                                 const float* __restrict__ Kr,
                                                 float* __restrict__ out) {
    int idx = blockIdx.x * 256 + threadIdx.x;
    int w = idx & 127, h = (idx >> 7) & 127, b = idx >> 14;
    float k[16];
#pragma unroll
    for (int i = 0; i < 16; ++i) k[i] = Kr[i];
    const float* p = cin + (size_t)idx * 16;
#pragma unroll
    for (int c = 0; c < 4; ++c) {
        float y00 = 0, y01 = 0, y10 = 0, y11 = 0;
#pragma unroll
        for (int sb = 0; sb < 4; ++sb) {
            float v = p[c * 4 + sb];
            y00 += v * k[sb*4];   y01 += v * k[sb*4+1];
            y10 += v * k[sb*4+2]; y11 += v * k[sb*4+3];
        }
        float* ob = out + ((size_t)(b * 4 + c) * 256 + 2 * h) * 256 + 2 * w;
        *(float2*)ob = make_float2(y00, y01);
        *(float2*)(ob + 256) = make_float2(y10, y11);
    }
}

// ---------------------------------------------------------------------------
// Implicit-GEMM 3x3 stride-1 conv, NHWC bf16, MFMA 16x16x32.
// Block 256 thr = 4 waves; tile 4 rows x 64 cols x NT couts; wave = 1 row.
// Register-prefetch pipeline over 32-channel K blocks.
// ---------------------------------------------------------------------------
template<int CIN, int COUT, int H, int W, bool STATS, bool OUTF32>
__global__ __launch_bounds__(256, 2) void conv_mfma(const ushort_t* __restrict__ in,
                                                    const ushort_t* __restrict__ wp,
                                                    const float* __restrict__ bias,
                                                    void* __restrict__ outp,
                                                    float2* __restrict__ stats) {
    constexpr int NT = (COUT < 64) ? COUT : 64;
    constexpr int NF = NT / 16;
    constexpr int NCB = CIN / 32;
    constexpr int IW = 66, NRI = 6;
    constexpr int AITER = NRI * IW * 4;         // 1584
    constexpr int CA = (AITER + 255) / 256;     // 7
    constexpr int BITER = 9 * NT * 4;
    constexpr int CB = (BITER + 255) / 256;
    constexpr int NB = COUT / NT, NW = W / 64, NH = H / 4;

    __shared__ ushort_t lA[NRI * IW * PAD];
    __shared__ ushort_t lB[9 * NT * PAD];
    __shared__ float2 sred[4][8];

    int bid = blockIdx.x;
    int nb = bid % NB; bid /= NB;
    int wt = bid % NW; bid /= NW;
    int ht = bid % NH;
    int b  = bid / NH;
    int h0 = ht * 4, w0 = wt * 64, n0 = nb * NT;
    int tid = threadIdx.x;
    int lane = tid & 63, wid = tid >> 6;
    int nl = lane & 15, quad = lane >> 4, ql = quad * 8;

    // precomputed staging offsets (cib-invariant)
    int ga[CA], la[CA];
#pragma unroll
    for (int r = 0; r < CA; ++r) {
        int i = tid + r * 256;
        ga[r] = -1; la[r] = 0;
        if (i < AITER) {
            int tr = i / (IW * 4); int rem = i - tr * (IW * 4);
            int p = rem >> 2, part = rem & 3;
            la[r] = (tr * IW + p) * PAD + part * 8;
            int ih = h0 - 1 + tr, iw = w0 - 1 + p;
            if ((unsigned)ih < (unsigned)H && (unsigned)iw < (unsigned)W)
                ga[r] = (ih * W + iw) * CIN + part * 8;
        }
    }
    int gb[CB], lb[CB];
#pragma unroll
    for (int r = 0; r < CB; ++r) {
        int i = tid + r * 256;
        gb[r] = -1; lb[r] = 0;
        if (i < BITER) {
            int tap = i / (NT * 4); int rem = i - tap * (NT * 4);
            int co = rem >> 2, part = rem & 3;
            gb[r] = (tap * COUT + n0 + co) * 32 + part * 8;
            lb[r] = (tap * NT + co) * PAD + part * 8;
        }
    }

    f32x4 acc[4][NF];
#pragma unroll
    for (int mf = 0; mf < 4; ++mf)
#pragma unroll
        for (int nf = 0; nf < NF; ++nf)
            acc[mf][nf] = (f32x4){0.f, 0.f, 0.f, 0.f};

    const ushort_t* ibase = in + (size_t)b * H * W * CIN;
    uint4 ra[CA], rb[CB];

    auto loadA = [&](int cib) {
#pragma unroll
        for (int r = 0; r < CA; ++r) {
            uint4 v = make_uint4(0, 0, 0, 0);
            if (ga[r] >= 0) v = *(const uint4*)(ibase + ga[r] + cib * 32);
            ra[r] = v;
        }
    };
    auto loadB = [&](int cib) {
        const ushort_t* wb = wp + (size_t)cib * 9 * COUT * 32;
#pragma unroll
        for (int r = 0; r < CB; ++r)
            if (gb[r] >= 0) rb[r] = *(const uint4*)(wb + gb[r]);
    };

    loadA(0); loadB(0);

    for (int cib = 0; cib < NCB; ++cib) {
        __syncthreads();
#pragma unroll
        for (int r = 0; r < CA; ++r)
            if (tid + r * 256 < AITER) *(uint4*)&lA[la[r]] = ra[r];
#pragma unroll
        for (int r = 0; r < CB; ++r)
            if (tid + r * 256 < BITER) *(uint4*)&lB[lb[r]] = rb[r];
        __syncthreads();
        if (cib + 1 < NCB) { loadA(cib + 1); loadB(cib + 1); }  // in flight during MFMA

#pragma unroll
        for (int tap = 0; tap < 9; ++tap) {
            const int kh = tap / 3, kw = tap % 3;
            short8 af[4];
#pragma unroll
            for (int mf = 0; mf < 4; ++mf)
                af[mf] = *(const short8*)&lA[((wid + kh) * IW + mf * 16 + nl + kw) * PAD + ql];
            short8 bf[NF];
#pragma unroll
            for (int nf = 0; nf < NF; ++nf)
                bf[nf] = *(const short8*)&lB[(tap * NT + nf * 16 + nl) * PAD + ql];
#pragma unroll
            for (int mf = 0; mf < 4; ++mf)
#pragma unroll
                for (int nf = 0; nf < NF; ++nf)
                    acc[mf][nf] = __builtin_amdgcn_mfma_f32_16x16x32_bf16(
                        af[mf], bf[nf], acc[mf][nf], 0, 0, 0);
        }
    }

    float bs[NF];
#pragma unroll
    for (int nf = 0; nf < NF; ++nf) bs[nf] = bias[n0 + nf * 16 + nl];

#pragma unroll
    for (int nf = 0; nf < NF; ++nf) {
        float s = 0.f, ss = 0.f;
#pragma unroll
        for (int mf = 0; mf < 4; ++mf) {
#pragma unroll
            for (int rg = 0; rg < 4; ++rg) {
                int c = mf * 16 + quad * 4 + rg;
                float v = acc[mf][nf][rg] + bs[nf];
                size_t oa = (((size_t)b * H + h0 + wid) * W + w0 + c) * COUT + n0 + nf * 16 + nl;
                if (OUTF32) ((float*)outp)[oa] = v;
                else        ((ushort_t*)outp)[oa] = f2bf(v);
                s += v; ss += v * v;
            }
        }
        if (STATS) {
            red_stats(s, ss);
            if (quad == 0 && (nl & 7) == 0) sred[wid][nf * 2 + (nl >> 3)] = make_float2(s, ss);
        }
    }
    if (STATS) {
        __syncthreads();
        if (tid < 2 * NF) {
            float2 t0 = sred[0][tid], t1 = sred[1][tid], t2 = sred[2][tid], t3 = sred[3][tid];
            float2* slot = &stats[(size_t)b * (COUT / 8) + (n0 >> 3) + tid];
            atomicAdd(&slot->x, t0.x + t1.x + t2.x + t3.x);
            atomicAdd(&slot->y, t0.y + t1.y + t2.y + t3.y);
        }
    }
}

// ---------------------------------------------------------------------------
// conv2 (3x3 stride-2) as dense parity conv: stride-1 2x2 taps over
// parity-packed input [64,64, (p,q,c)=4*64 ch]; 9/16 tap combos valid.
// in: A1 NHWC bf16 [16,128,128,64]; out: A2 NHWC bf16 [16,64,64,128].
// ---------------------------------------------------------------------------
__global__ __launch_bounds__(256, 2) void conv2p_mfma(const ushort_t* __restrict__ in,
                                                      const ushort_t* __restrict__ wp,
                                                      const float* __restrict__ bias,
                                                      ushort_t* __restrict__ outp,
                                                      float2* __restrict__ stats) {
    constexpr int IW = 65, NRI = 5, NF = 4, NT = 64;
    constexpr int AITER = NRI * IW * 4;       // 1300
    constexpr int CA = 6;
    constexpr int CB = 4;                     // 4*64*4/256
    __shared__ ushort_t lA[NRI * IW * PAD];
    __shared__ ushort_t lB[4 * NT * PAD];
    __shared__ float2 sred[4][8];

    int bid = blockIdx.x;
    int nb = bid & 1; bid >>= 1;
    int ht = bid & 15;
    int b  = bid >> 4;
    int h0 = ht * 4, n0 = nb * 64;
    int tid = threadIdx.x;
    int lane = tid & 63, wid = tid >> 6;
    int nl = lane & 15, quad = lane >> 4, ql = quad * 8;

    int r2[CA], c2[CA], la[CA], g4[CA];
#pragma unroll
    for (int r = 0; r < CA; ++r) {
        int i = tid + r * 256;
        r2[r] = -1000; c2[r] = 0; la[r] = 0; g4[r] = 0;
        if (i < AITER) {
            int tr = i / (IW * 4); int rem = i - tr * (IW * 4);
            int p = rem >> 2, part = rem & 3;
            r2[r] = 2 * (h0 - 1 + tr);
            c2[r] = 2 * (p - 1);
            la[r] = (tr * IW + p) * PAD + part * 8;
            g4[r] = part * 8;
        }
    }
    int gb[CB], lb[CB];
#pragma unroll
    for (int r = 0; r < CB; ++r) {
        int i = tid + r * 256;
        int tap = i >> 8, co = (i >> 2) & 63, part = i & 3;
        gb[r] = (tap * 128 + n0 + co) * 32 + part * 8;
        lb[r] = (tap * NT + co) * PAD + part * 8;
    }

    f32x4 acc[4][NF];
#pragma unroll
    for (int mf = 0; mf < 4; ++mf)
#pragma unroll
        for (int nf = 0; nf < NF; ++nf)
            acc[mf][nf] = (f32x4){0.f, 0.f, 0.f, 0.f};

    const ushort_t* ibase = in + (size_t)b * 128 * 128 * 64;
    uint4 ra[CA], rb[CB];

    auto loadA = [&](int cib) {
        const int p = cib >> 2, q = (cib >> 1) & 1, ch32 = (cib & 1) * 32;
#pragma unroll
        for (int r = 0; r < CA; ++r) {
            int ih = r2[r] + p, iw = c2[r] + q;
            uint4 v = make_uint4(0, 0, 0, 0);
            if ((unsigned)ih < 128u && (unsigned)iw < 128u)
                v = *(const uint4*)(ibase + ((ih << 7) + iw) * 64 + ch32 + g4[r]);
            ra[r] = v;
        }
    };
    auto loadB = [&](int cib) {
        const ushort_t* wb = wp + (size_t)cib * 4 * 128 * 32;
#pragma unroll
        for (int r = 0; r < CB; ++r)
            rb[r] = *(const uint4*)(wb + gb[r]);
    };

    loadA(0); loadB(0);

#pragma unroll
    for (int cib = 0; cib < 8; ++cib) {
        const int p = cib >> 2, q = (cib >> 1) & 1;
        __syncthreads();
#pragma unroll
        for (int r = 0; r < CA; ++r)
            if (tid + r * 256 < AITER) *(uint4*)&lA[la[r]] = ra[r];
#pragma unroll
        for (int r = 0; r < CB; ++r) *(uint4*)&lB[lb[r]] = rb[r];
        __syncthreads();
        if (cib + 1 < 8) { loadA(cib + 1); loadB(cib + 1); }

#pragma unroll
        for (int kh = 0; kh < 2; ++kh) {
#pragma unroll
            for (int kw = 0; kw < 2; ++kw) {
                if ((kh == 1 || p == 1) && (kw == 1 || q == 1)) {
                    short8 af[4];
#pragma unroll
                    for (int mf = 0; mf < 4; ++mf)
                        af[mf] = *(const short8*)&lA[((wid + kh) * IW + mf * 16 + nl + kw) * PAD + ql];
                    short8 bf[NF];
#pragma unroll
                    for (int nf = 0; nf < NF; ++nf)
                        bf[nf] = *(const short8*)&lB[((kh * 2 + kw) * NT + nf * 16 + nl) * PAD + ql];
#pragma unroll
                    for (int mf = 0; mf < 4; ++mf)
#pragma unroll
                        for (int nf = 0; nf < NF; ++nf)
                            acc[mf][nf] = __builtin_amdgcn_mfma_f32_16x16x32_bf16(
                                af[mf], bf[nf], acc[mf][nf], 0, 0, 0);
                }
            }
        }
    }

    float bs[NF];
#pragma unroll
    for (int nf = 0; nf < NF; ++nf) bs[nf] = bias[n0 + nf * 16 + nl];
#pragma unroll
    for (int nf = 0; nf < NF; ++nf) {
        float s = 0.f, ss = 0.f;
#pragma unroll
        for (int mf = 0; mf < 4; ++mf) {
#pragma unroll
            for (int rg = 0; rg < 4; ++rg) {
                int c = mf * 16 + quad * 4 + rg;
                float v = acc[mf][nf][rg] + bs[nf];
                size_t oa = (((size_t)b * 64 + h0 + wid) * 64 + c) * 128 + n0 + nf * 16 + nl;
                outp[oa] = f2bf(v);
                s += v; ss += v * v;
            }
        }
        red_stats(s, ss);
        if (quad == 0 && (nl & 7) == 0) sred[wid][nf * 2 + (nl >> 3)] = make_float2(s, ss);
    }
    __syncthreads();
    if (tid < 8) {
        float2 t0 = sred[0][tid], t1 = sred[1][tid], t2 = sred[2][tid], t3 = sred[3][tid];
        float2* slot = &stats[(size_t)b * 16 + (n0 >> 3) + tid];
        atomicAdd(&slot->x, t0.x + t1.x + t2.x + t3.x);
        atomicAdd(&slot->y, t0.y + t1.y + t2.y + t3.y);
    }
}

// ---------------------------------------------------------------------------
// ConvTranspose 4x4 s2 p1, 4 output-parity phases of 2x2 taps.
// in A4 NHWC bf16 [16,64,64,128] -> out A5 NHWC bf16 [16,128,128,64]
// ---------------------------------------------------------------------------
__global__ __launch_bounds__(256, 2) void convt_mfma(const ushort_t* __restrict__ in,
                                                     const ushort_t* __restrict__ wp,
                                                     const float* __restrict__ bias,
                                                     ushort_t* __restrict__ outp,
                                                     float2* __restrict__ stats) {
    constexpr int CIN = 128, COUT = 64, NT = 64, NF = 4;
    constexpr int IW = 66, NRI = 5;
    constexpr int AITER = NRI * IW * 4;      // 1320
    constexpr int CA = 6, CB = 4;
    __shared__ ushort_t lA[NRI * IW * PAD];
    __shared__ ushort_t lB[4 * NT * PAD];
    __shared__ float2 sred[4][8];

    int bid = blockIdx.x;
    int ht = bid & 15; bid >>= 4;
    int ph = bid & 3;
    int b  = bid >> 2;
    int eh = ph >> 1, ew = ph & 1;
    int ho0 = ht * 4;
    int tid = threadIdx.x;
    int lane = tid & 63, wid = tid >> 6;
    int nl = lane & 15, quad = lane >> 4, ql = quad * 8;

    int ga[CA], la[CA];
#pragma unroll
    for (int r = 0; r < CA; ++r) {
        int i = tid + r * 256;
        ga[r] = -1; la[r] = 0;
        if (i < AITER) {
            int tr = i / (IW * 4); int rem = i - tr * (IW * 4);
            int p = rem >> 2, part = rem & 3;
            la[r] = (tr * IW + p) * PAD + part * 8;
            int ih = ho0 + tr - (1 - eh), iw = p - 1;
            if ((unsigned)ih < 64u && (unsigned)iw < 64u)
                ga[r] = (ih * 64 + iw) * CIN + part * 8;
        }
    }
    int gb[CB], lb[CB];
#pragma unroll
    for (int r = 0; r < CB; ++r) {
        int i = tid + r * 256;
        int tap = i >> 8, co = (i >> 2) & 63, part = i & 3;
        gb[r] = (tap * COUT + co) * 32 + part * 8;
        lb[r] = (tap * NT + co) * PAD + part * 8;
    }

    f32x4 acc[4][NF];
#pragma unroll
    for (int mf = 0; mf < 4; ++mf)
#pragma unroll
        for (int nf = 0; nf < NF; ++nf)
            acc[mf][nf] = (f32x4){0.f, 0.f, 0.f, 0.f};

    const ushort_t* ibase = in + (size_t)b * 64 * 64 * CIN;
    uint4 ra[CA], rb[CB];

    auto loadA = [&](int cib) {
#pragma unroll
        for (int r = 0; r < CA; ++r) {
            uint4 v = make_uint4(0, 0, 0, 0);
            if (ga[r] >= 0) v = *(const uint4*)(ibase + ga[r] + cib * 32);
            ra[r] = v;
        }
    };
    auto loadB = [&](int cib) {
        const ushort_t* wb = wp + ((size_t)ph * 4 + cib) * 4 * COUT * 32;
#pragma unroll
        for (int r = 0; r < CB; ++r)
            rb[r] = *(const uint4*)(wb + gb[r]);
    };

    loadA(0); loadB(0);

    for (int cib = 0; cib < 4; ++cib) {
        __syncthreads();
#pragma unroll
        for (int r = 0; r < CA; ++r)
            if (tid + r * 256 < AITER) *(uint4*)&lA[la[r]] = ra[r];
#pragma unroll
        for (int r = 0; r < CB; ++r) *(uint4*)&lB[lb[r]] = rb[r];
        __syncthreads();
        if (cib + 1 < 4) { loadA(cib + 1); loadB(cib + 1); }

#pragma unroll
        for (int tap = 0; tap < 4; ++tap) {
            const int rs = tap >> 1, cs = tap & 1;
            short8 af[4];
#pragma unroll
            for (int mf = 0; mf < 4; ++mf)
                af[mf] = *(const short8*)&lA[((wid + rs) * IW + mf * 16 + nl + cs + ew) * PAD + ql];
            short8 bf[NF];
#pragma unroll
            for (int nf = 0; nf < NF; ++nf)
                bf[nf] = *(const short8*)&lB[(tap * NT + nf * 16 + nl) * PAD + ql];
#pragma unroll
            for (int mf = 0; mf < 4; ++mf)
#pragma unroll
                for (int nf = 0; nf < NF; ++nf)
                    acc[mf][nf] = __builtin_amdgcn_mfma_f32_16x16x32_bf16(
                        af[mf], bf[nf], acc[mf][nf], 0, 0, 0);
        }
    }

    float bs[NF];
#pragma unroll
    for (int nf = 0; nf < NF; ++nf) bs[nf] = bias[nf * 16 + nl];
    int oh = 2 * (ho0 + wid) + eh;
#pragma unroll
    for (int nf = 0; nf < NF; ++nf) {
        float s = 0.f, ss = 0.f;
#pragma unroll
        for (int mf = 0; mf < 4; ++mf) {
#pragma unroll
            for (int rg = 0; rg < 4; ++rg) {
                int wo = mf * 16 + quad * 4 + rg;
                float v = acc[mf][nf][rg] + bs[nf];
                size_t oa = (((size_t)b * 128 + oh) * 128 + 2 * wo + ew) * 64 + nf * 16 + nl;
                outp[oa] = f2bf(v);
                s += v; ss += v * v;
            }
        }
        red_stats(s, ss);
        if (quad == 0 && (nl & 7) == 0) sred[wid][nf * 2 + (nl >> 3)] = make_float2(s, ss);
    }
    __syncthreads();
    if (tid < 8) {
        float2 t0 = sred[0][tid], t1 = sred[1][tid], t2 = sred[2][tid], t3 = sred[3][tid];
        float2* slot = &stats[(size_t)b * 8 + tid];
        atomicAdd(&slot->x, t0.x + t1.x + t2.x + t3.x);
        atomicAdd(&slot->y, t0.y + t1.y + t2.y + t3.y);
    }
}

// ---------------------------------------------------------------------------
// GroupNorm(8ch/group) + ReLU over NHWC bf16, 8 channels per thread.
// ---------------------------------------------------------------------------
template<int C, int HW>
__global__ __launch_bounds__(256) void gn_relu(ushort_t* __restrict__ data,
                                               const float2* __restrict__ stats,
                                               const float* __restrict__ gamma,
                                               const float* __restrict__ beta,
                                               float invC) {
    int idx = blockIdx.x * 256 + threadIdx.x;
    int e8 = idx * 8;
    int c0 = e8 & (C - 1);
    int b = e8 / (HW * C);
    float2 st = stats[(size_t)b * (C / 8) + (c0 >> 3)];
    float mean = st.x * invC;
    float var = st.y * invC - mean * mean;
    float rstd = rsqrtf(var + 1e-5f);
    uint4 v = ((const uint4*)data)[idx];
    uint_t u[4] = {v.x, v.y, v.z, v.w};
    uint_t r[4];
#pragma unroll
    for (int p = 0; p < 4; ++p) {
        int c = c0 + p * 2;
        float f0 = bf2f((ushort_t)(u[p] & 0xffffu));
        float f1 = bf2f((ushort_t)(u[p] >> 16));
        f0 = fmaxf((f0 - mean) * rstd * gamma[c] + beta[c], 0.f);
        f1 = fmaxf((f1 - mean) * rstd * gamma[c + 1] + beta[c + 1], 0.f);
        r[p] = (uint_t)f2bf(f0) | ((uint_t)f2bf(f1) << 16);
    }
    ((uint4*)data)[idx] = make_uint4(r[0], r[1], r[2], r[3]);
}

// ---------------------------------------------------------------------------
extern "C" void kernel_launch(void* const* d_in, const int* in_sizes, int n_in,
                              void* d_out, int out_size, void* d_ws, size_t ws_size,
                              hipStream_t stream) {
    const float* x   = (const float*)d_in[0];
    const float* Kd  = (const float*)d_in[1];
    const float* Kr  = (const float*)d_in[2];
    const float* W1  = (const float*)d_in[3];  const float* b1  = (const float*)d_in[4];
    const float* g1  = (const float*)d_in[5];  const float* be1 = (const float*)d_in[6];
    const float* W2  = (const float*)d_in[7];  const float* b2  = (const float*)d_in[8];
    const float* g2  = (const float*)d_in[9];  const float* be2 = (const float*)d_in[10];
    const float* W3  = (const float*)d_in[11]; const float* b3  = (const float*)d_in[12];
    const float* g3  = (const float*)d_in[13]; const float* be3 = (const float*)d_in[14];
    const float* W4  = (const float*)d_in[15]; const float* b4  = (const float*)d_in[16];
    const float* g4  = (const float*)d_in[17]; const float* be4 = (const float*)d_in[18];
    const float* Wt  = (const float*)d_in[19]; const float* bt  = (const float*)d_in[20];
    const float* g5  = (const float*)d_in[21]; const float* be5 = (const float*)d_in[22];
    const float* W6  = (const float*)d_in[23]; const float* b6  = (const float*)d_in[24];

    ushort_t* U  = (ushort_t*)d_ws;           // 8,388,608 elems
    ushort_t* V  = U + 8388608;               // 16,777,216 elems
    ushort_t* WP = V + 16777216;              // 879,616 elems
    ushort_t* wp1 = WP;
    ushort_t* wp2 = WP + 18432;
    ushort_t* wp3 = WP + 149504;
    ushort_t* wp4 = WP + 444416;
    ushort_t* wpt = WP + 739328;
    ushort_t* wp6 = WP + 870400;
    float2* stats = (float2*)(WP + 879616);   // 1280 float2
    float* out = (float*)d_out;

    hipMemsetAsync(stats, 0, 1280 * sizeof(float2), stream);

    pack_all<<<3436, 256, 0, stream>>>(W1, W2, W3, W4, Wt, W6, WP);

    // DWT: x -> U (A0 [16,128,128,32] bf16)
    dwt_nhwc<<<1024, 256, 0, stream>>>(x, Kd, U);

    // conv1 32->64 @128x128: U -> V
    conv_mfma<32, 64, 128, 128, true, false>
        <<<1024, 256, 0, stream>>>(U, wp1, b1, V, stats + 0);
    gn_relu<64, 16384><<<8192, 256, 0, stream>>>(V, stats + 0, g1, be1, 1.f / 131072.f);

    // conv2 (parity) 64->128 s2: V -> U (A2 [16,64,64,128])
    conv2p_mfma<<<512, 256, 0, stream>>>(V, wp2, b2, U, stats + 128);
    gn_relu<128, 4096><<<4096, 256, 0, stream>>>(U, stats + 128, g2, be2, 1.f / 32768.f);

    // conv3 128->256 @64x64: U -> V
    conv_mfma<128, 256, 64, 64, true, false>
        <<<1024, 256, 0, stream>>>(U, wp3, b3, V, stats + 384);
    gn_relu<256, 4096><<<8192, 256, 0, stream>>>(V, stats + 384, g3, be3, 1.f / 32768.f);

    // conv4 256->128 @64x64: V -> U (A4)
    conv_mfma<256, 128, 64, 64, true, false>
        <<<512, 256, 0, stream>>>(V, wp4, b4, U, stats + 896);
    gn_relu<128, 4096><<<4096, 256, 0, stream>>>(U, stats + 896, g4, be4, 1.f / 32768.f);

    // convT 128->64 x2: U -> V (A5 [16,128,128,64])
    convt_mfma<<<1024, 256, 0, stream>>>(U, wpt, bt, V, stats + 1152);
    gn_relu<64, 16384><<<8192, 256, 0, stream>>>(V, stats + 1152, g5, be5, 1.f / 131072.f);

    // conv6 64->16 @128x128: V -> U (A6 fp32 NHWC [16,128,128,16])
    conv_mfma<64, 16, 128, 128, false, true>
        <<<1024, 256, 0, stream>>>(V, wp6, b6, U, nullptr);

    // IDWT: U -> out
    idwt_nhwc<<<1024, 256, 0, stream>>>((const float*)U, Kr, out);
}

// Round 4
// 502.108 us; speedup vs baseline: 15.8352x; 1.0545x over previous
//
#include <hip/hip_runtime.h>

typedef unsigned short ushort_t;
typedef unsigned int uint_t;
typedef __attribute__((ext_vector_type(8))) short short8;
typedef __attribute__((ext_vector_type(4))) float f32x4;

#define PAD 40   // staging LDS elems per pixel/co row: bank stride 20 -> 2-way (free)

__device__ __forceinline__ ushort_t f2bf(float f) {
    uint_t u = __float_as_uint(f);
    u = (u + 0x7FFFu + ((u >> 16) & 1u)) >> 16;
    return (ushort_t)u;
}
__device__ __forceinline__ float bf2f(ushort_t h) {
    return __uint_as_float(((uint_t)h) << 16);
}

__device__ __forceinline__ void red_stats(float& s, float& ss) {
    s += __shfl_xor(s, 16); ss += __shfl_xor(ss, 16);
    s += __shfl_xor(s, 32); ss += __shfl_xor(ss, 32);
    s += __shfl_xor(s, 1);  ss += __shfl_xor(ss, 1);
    s += __shfl_xor(s, 2);  ss += __shfl_xor(ss, 2);
    s += __shfl_xor(s, 4);  ss += __shfl_xor(ss, 4);
}

// normalize 8 bf16 channels with (scale,shift) from LDS table + ReLU
__device__ __forceinline__ uint4 gn8(uint4 v, const float2* ss) {
    uint_t u[4] = {v.x, v.y, v.z, v.w};
    uint_t r[4];
#pragma unroll
    for (int p = 0; p < 4; ++p) {
        float2 s0 = ss[2 * p], s1 = ss[2 * p + 1];
        float f0 = fmaxf(bf2f((ushort_t)(u[p] & 0xffffu)) * s0.x + s0.y, 0.f);
        float f1 = fmaxf(bf2f((ushort_t)(u[p] >> 16)) * s1.x + s1.y, 0.f);
        r[p] = (uint_t)f2bf(f0) | ((uint_t)f2bf(f1) << 16);
    }
    return make_uint4(r[0], r[1], r[2], r[3]);
}

// fill per-channel (scale, shift) LDS table from raw (sum, sumsq) stats
template<int C>
__device__ __forceinline__ void fill_ss(float2* sshare, const float2* __restrict__ instats,
                                        const float* __restrict__ gamma,
                                        const float* __restrict__ beta,
                                        int b, float invC, int tid) {
    for (int c = tid; c < C; c += 256) {
        float2 st = instats[(size_t)b * (C / 8) + (c >> 3)];
        float mean = st.x * invC;
        float rstd = rsqrtf(st.y * invC - mean * mean + 1e-5f);
        float sc = gamma[c] * rstd;
        sshare[c] = make_float2(sc, beta[c] - mean * sc);
    }
}

// ---------------------------------------------------------------------------
// Weight packing (one merged kernel)
// ---------------------------------------------------------------------------
template<int CIN, int COUT>
__device__ __forceinline__ void pack3(const float* __restrict__ W, ushort_t* __restrict__ wp, int idx) {
    int kk = idx & 31;
    int t = idx >> 5;
    int co = t % COUT; t /= COUT;
    int tap = t % 9;
    int cib = t / 9;
    wp[idx] = f2bf(W[(co * CIN + cib * 32 + kk) * 9 + tap]);
}

__device__ __forceinline__ void pack2p(const float* __restrict__ W2, ushort_t* __restrict__ wp, int idx) {
    int kk = idx & 31;
    int co = (idx >> 5) & 127;
    int tap = (idx >> 12) & 3;
    int cib = idx >> 14;
    int p = cib >> 2, q = (cib >> 1) & 1, chalf = cib & 1;
    int kh = 2 * (tap >> 1) + p - 1;
    int kw = 2 * (tap & 1) + q - 1;
    float v = 0.f;
    if (kh >= 0 && kh < 3 && kw >= 0 && kw < 3)
        v = W2[(co * 64 + chalf * 32 + kk) * 9 + kh * 3 + kw];
    wp[idx] = f2bf(v);
}

__device__ __forceinline__ void packt(const float* __restrict__ Wt, ushort_t* __restrict__ wp, int idx) {
    int kk = idx & 31;
    int t = idx >> 5;
    int co = t & 63; t >>= 6;
    int tap = t & 3; t >>= 2;
    int cib = t & 3;
    int ph = t >> 2;
    int rs = tap >> 1, cs = tap & 1;
    int eh = ph >> 1, ew = ph & 1;
    int kh = eh ? (rs ? 0 : 2) : (rs ? 1 : 3);
    int kw = ew ? (cs ? 0 : 2) : (cs ? 1 : 3);
    wp[idx] = f2bf(Wt[((cib * 32 + kk) * 64 + co) * 16 + kh * 4 + kw]);
}

__global__ __launch_bounds__(256) void pack_all(const float* __restrict__ W1,
                                                const float* __restrict__ W2,
                                                const float* __restrict__ W3,
                                                const float* __restrict__ W4,
                                                const float* __restrict__ Wt,
                                                const float* __restrict__ W6,
                                                ushort_t* __restrict__ WP) {
    int idx = blockIdx.x * 256 + threadIdx.x;
    if (idx < 18432)        pack3<32, 64>(W1, WP, idx);
    else if (idx < 149504)  pack2p(W2, WP + 18432, idx - 18432);
    else if (idx < 444416)  pack3<128, 256>(W3, WP + 149504, idx - 149504);
    else if (idx < 739328)  pack3<256, 128>(W4, WP + 444416, idx - 444416);
    else if (idx < 870400)  packt(Wt, WP + 739328, idx - 739328);
    else if (idx < 879616)  pack3<64, 16>(W6, WP + 870400, idx - 870400);
}

// ---------------------------------------------------------------------------
// DWT: x NCHW fp32 [16,8,256,256] -> NHWC bf16 [16,128,128,32]
// ---------------------------------------------------------------------------
__global__ __launch_bounds__(256) void dwt_nhwc(const float* __restrict__ x,
                                                const float* __restrict__ Kd,
                                                ushort_t* __restrict__ out) {
    int idx = blockIdx.x * 256 + threadIdx.x;
    int w = idx & 127, h = (idx >> 7) & 127, b = idx >> 14;
    float k[16];
#pragma unroll
    for (int i = 0; i < 16; ++i) k[i] = Kd[i];
    const float* xb = x + (size_t)b * 8 * 65536;
    uint_t uu[16];
#pragma unroll
    for (int ci = 0; ci < 8; ++ci) {
        const float* p = xb + ci * 65536 + (2 * h) * 256 + 2 * w;
        float2 r0 = *(const float2*)p;
        float2 r1 = *(const float2*)(p + 256);
        ushort_t o[4];
#pragma unroll
        for (int sb = 0; sb < 4; ++sb) {
            float v = r0.x * k[sb*4] + r0.y * k[sb*4+1] + r1.x * k[sb*4+2] + r1.y * k[sb*4+3];
            o[sb] = f2bf(v);
        }
        uu[ci*2]   = (uint_t)o[0] | ((uint_t)o[1] << 16);
        uu[ci*2+1] = (uint_t)o[2] | ((uint_t)o[3] << 16);
    }
    uint4* dst = (uint4*)(out + (size_t)idx * 32);
    dst[0] = make_uint4(uu[0], uu[1], uu[2], uu[3]);
    dst[1] = make_uint4(uu[4], uu[5], uu[6], uu[7]);
    dst[2] = make_uint4(uu[8], uu[9], uu[10], uu[11]);
    dst[3] = make_uint4(uu[12], uu[13], uu[14], uu[15]);
}

// ---------------------------------------------------------------------------
// IDWT: in NHWC bf16 [16,128,128,16] -> out NCHW fp32 [16,4,256,256]
// ---------------------------------------------------------------------------
__global__ __launch_bounds__(256) void idwt_nhwc(const ushort_t* __restrict__ cin,
                                                 const float* __restrict__ Kr,
                                                 float* __restrict__ out) {
    int idx = blockIdx.x * 256 + threadIdx.x;
    int w = idx & 127, h = (idx >> 7) & 127, b = idx >> 14;
    float k[16];
#pragma unroll
    for (int i = 0; i < 16; ++i) k[i] = Kr[i];
    const uint4* pv = (const uint4*)(cin + (size_t)idx * 16);
    uint4 v0 = pv[0], v1 = pv[1];
    uint_t uw[8] = {v0.x, v0.y, v0.z, v0.w, v1.x, v1.y, v1.z, v1.w};
    float cs[16];
#pragma unroll
    for (int i = 0; i < 8; ++i) {
        cs[2*i]   = bf2f((ushort_t)(uw[i] & 0xffffu));
        cs[2*i+1] = bf2f((ushort_t)(uw[i] >> 16));
    }
#pragma unroll
    for (int c = 0; c < 4; ++c) {
        float y00 = 0, y01 = 0, y10 = 0, y11 = 0;
#pragma unroll
        for (int sb = 0; sb < 4; ++sb) {
            float v = cs[c * 4 + sb];
            y00 += v * k[sb*4];   y01 += v * k[sb*4+1];
            y10 += v * k[sb*4+2]; y11 += v * k[sb*4+3];
        }
        float* ob = out + ((size_t)(b * 4 + c) * 256 + 2 * h) * 256 + 2 * w;
        *(float2*)ob = make_float2(y00, y01);
        *(float2*)(ob + 256) = make_float2(y10, y11);
    }
}

// ---------------------------------------------------------------------------
// Implicit-GEMM 3x3 stride-1 conv, NHWC bf16, MFMA 16x16x32.
// Optional fused input-GN+ReLU (consumer side), fused output GN stats,
// LDS-transposed coalesced epilogue stores.
// ---------------------------------------------------------------------------
template<int CIN, int COUT, int H, int W, bool STATS, bool GNIN>
__global__ __launch_bounds__(256, 2) void conv_mfma(const ushort_t* __restrict__ in,
                                                    const ushort_t* __restrict__ wp,
                                                    const float* __restrict__ bias,
                                                    ushort_t* __restrict__ outp,
                                                    float2* __restrict__ stats,
                                                    const float2* __restrict__ instats,
                                                    const float* __restrict__ gamma,
                                                    const float* __restrict__ beta,
                                                    float invC) {
    constexpr int NT = (COUT < 64) ? COUT : 64;
    constexpr int NF = NT / 16;
    constexpr int NCB = CIN / 32;
    constexpr int IW = 66, NRI = 6;
    constexpr int AITER = NRI * IW * 4;
    constexpr int CA = (AITER + 255) / 256;
    constexpr int BITER = 9 * NT * 4;
    constexpr int CB = (BITER + 255) / 256;
    constexpr int NB = COUT / NT, NW = W / 64, NH = H / 4;
    constexpr int EP = NT + 8;                    // epilogue row elems (16B-aligned rows)

    __shared__ ushort_t smem[NRI * IW * PAD + 9 * NT * PAD];
    __shared__ float2 sred[4][8];
    __shared__ float2 sshare[CIN];
    ushort_t* lA = smem;
    ushort_t* lB = smem + NRI * IW * PAD;
    ushort_t* lE = smem;                          // epilogue overlay: 256*EP elems

    int bid = blockIdx.x;
    int nb = bid % NB; bid /= NB;
    int wt = bid % NW; bid /= NW;
    int ht = bid % NH;
    int b  = bid / NH;
    int h0 = ht * 4, w0 = wt * 64, n0 = nb * NT;
    int tid = threadIdx.x;
    int lane = tid & 63, wid = tid >> 6;
    int nl = lane & 15, quad = lane >> 4, ql = quad * 8;

    if (GNIN) {
        fill_ss<CIN>(sshare, instats, gamma, beta, b, invC, tid);
        __syncthreads();
    }

    int ga[CA], la[CA], pr[CA];
#pragma unroll
    for (int r = 0; r < CA; ++r) {
        int i = tid + r * 256;
        ga[r] = -1; la[r] = 0; pr[r] = 0;
        if (i < AITER) {
            int tr = i / (IW * 4); int rem = i - tr * (IW * 4);
            int p = rem >> 2, part = rem & 3;
            la[r] = (tr * IW + p) * PAD + part * 8;
            pr[r] = part;
            int ih = h0 - 1 + tr, iw = w0 - 1 + p;
            if ((unsigned)ih < (unsigned)H && (unsigned)iw < (unsigned)W)
                ga[r] = (ih * W + iw) * CIN + part * 8;
        }
    }
    int gb[CB], lb[CB];
#pragma unroll
    for (int r = 0; r < CB; ++r) {
        int i = tid + r * 256;
        gb[r] = -1; lb[r] = 0;
        if (i < BITER) {
            int tap = i / (NT * 4); int rem = i - tap * (NT * 4);
            int co = rem >> 2, part = rem & 3;
            gb[r] = (tap * COUT + n0 + co) * 32 + part * 8;
            lb[r] = (tap * NT + co) * PAD + part * 8;
        }
    }

    f32x4 acc[4][NF];
#pragma unroll
    for (int mf = 0; mf < 4; ++mf)
#pragma unroll
        for (int nf = 0; nf < NF; ++nf)
            acc[mf][nf] = (f32x4){0.f, 0.f, 0.f, 0.f};

    const ushort_t* ibase = in + (size_t)b * H * W * CIN;
    uint4 ra[CA], rb[CB];

    auto loadA = [&](int cib) {
#pragma unroll
        for (int r = 0; r < CA; ++r) {
            uint4 v = make_uint4(0, 0, 0, 0);
            if (ga[r] >= 0) {
                v = *(const uint4*)(ibase + ga[r] + cib * 32);
                if (GNIN) v = gn8(v, &sshare[cib * 32 + pr[r] * 8]);
            }
            ra[r] = v;
        }
    };
    auto loadB = [&](int cib) {
        const ushort_t* wb = wp + (size_t)cib * 9 * COUT * 32;
#pragma unroll
        for (int r = 0; r < CB; ++r)
            if (gb[r] >= 0) rb[r] = *(const uint4*)(wb + gb[r]);
    };

    loadA(0); loadB(0);

    for (int cib = 0; cib < NCB; ++cib) {
        __syncthreads();
#pragma unroll
        for (int r = 0; r < CA; ++r)
            if (tid + r * 256 < AITER) *(uint4*)&lA[la[r]] = ra[r];
#pragma unroll
        for (int r = 0; r < CB; ++r)
            if (tid + r * 256 < BITER) *(uint4*)&lB[lb[r]] = rb[r];
        __syncthreads();
        if (cib + 1 < NCB) { loadA(cib + 1); loadB(cib + 1); }

#pragma unroll
        for (int tap = 0; tap < 9; ++tap) {
            const int kh = tap / 3, kw = tap % 3;
            short8 af[4];
#pragma unroll
            for (int mf = 0; mf < 4; ++mf)
                af[mf] = *(const short8*)&lA[((wid + kh) * IW + mf * 16 + nl + kw) * PAD + ql];
            short8 bf[NF];
#pragma unroll
            for (int nf = 0; nf < NF; ++nf)
                bf[nf] = *(const short8*)&lB[(tap * NT + nf * 16 + nl) * PAD + ql];
#pragma unroll
            for (int mf = 0; mf < 4; ++mf)
#pragma unroll
                for (int nf = 0; nf < NF; ++nf)
                    acc[mf][nf] = __builtin_amdgcn_mfma_f32_16x16x32_bf16(
                        af[mf], bf[nf], acc[mf][nf], 0, 0, 0);
        }
    }

    float bs[NF];
#pragma unroll
    for (int nf = 0; nf < NF; ++nf) bs[nf] = bias[n0 + nf * 16 + nl];

    // fused GN stats from accumulators
    if (STATS) {
#pragma unroll
        for (int nf = 0; nf < NF; ++nf) {
            float s = 0.f, ss = 0.f;
#pragma unroll
            for (int mf = 0; mf < 4; ++mf)
#pragma unroll
                for (int rg = 0; rg < 4; ++rg) {
                    float v = acc[mf][nf][rg] + bs[nf];
                    s += v; ss += v * v;
                }
            red_stats(s, ss);
            if (quad == 0 && (nl & 7) == 0) sred[wid][nf * 2 + (nl >> 3)] = make_float2(s, ss);
        }
    }

    // LDS-transposed coalesced store
    __syncthreads();
#pragma unroll
    for (int mf = 0; mf < 4; ++mf)
#pragma unroll
        for (int nf = 0; nf < NF; ++nf)
#pragma unroll
            for (int rg = 0; rg < 4; ++rg) {
                int px = wid * 64 + mf * 16 + quad * 4 + rg;
                lE[px * EP + nf * 16 + nl] = f2bf(acc[mf][nf][rg] + bs[nf]);
            }
    __syncthreads();
#pragma unroll
    for (int it = 0; it < NT / 8; ++it) {
        int idx = it * 256 + tid;
        int px = idx / (NT / 8), ck = idx % (NT / 8);
        int row = px >> 6, col = px & 63;
        uint4 v = *(const uint4*)&lE[px * EP + ck * 8];
        *(uint4*)(outp + (((size_t)b * H + h0 + row) * W + w0 + col) * COUT + n0 + ck * 8) = v;
    }
    if (STATS && tid < 2 * NF) {
        float2 t0 = sred[0][tid], t1 = sred[1][tid], t2 = sred[2][tid], t3 = sred[3][tid];
        float2* slot = &stats[(size_t)b * (COUT / 8) + (n0 >> 3) + tid];
        atomicAdd(&slot->x, t0.x + t1.x + t2.x + t3.x);
        atomicAdd(&slot->y, t0.y + t1.y + t2.y + t3.y);
    }
}

// ---------------------------------------------------------------------------
// conv2 (3x3 stride-2) as dense parity conv (input GN1 fused).
// in A1 raw [16,128,128,64] bf16 -> out A2 raw [16,64,64,128] bf16
// ---------------------------------------------------------------------------
__global__ __launch_bounds__(256, 2) void conv2p_mfma(const ushort_t* __restrict__ in,
                                                      const ushort_t* __restrict__ wp,
                                                      const float* __restrict__ bias,
                                                      ushort_t* __restrict__ outp,
                                                      float2* __restrict__ stats,
                                                      const float2* __restrict__ instats,
                                                      const float* __restrict__ gamma,
                                                      const float* __restrict__ beta,
                                                      float invC) {
    constexpr int IW = 65, NRI = 5, NF = 4, NT = 64;
    constexpr int AITER = NRI * IW * 4;
    constexpr int CA = 6, CB = 4;
    constexpr int EP = NT + 8;
    __shared__ ushort_t smem[NRI * IW * PAD + 4 * NT * PAD];
    __shared__ float2 sred[4][8];
    __shared__ float2 sshare[64];
    ushort_t* lA = smem;
    ushort_t* lB = smem + NRI * IW * PAD;
    ushort_t* lE = smem;

    int bid = blockIdx.x;
    int nb = bid & 1; bid >>= 1;
    int ht = bid & 15;
    int b  = bid >> 4;
    int h0 = ht * 4, n0 = nb * 64;
    int tid = threadIdx.x;
    int lane = tid & 63, wid = tid >> 6;
    int nl = lane & 15, quad = lane >> 4, ql = quad * 8;

    fill_ss<64>(sshare, instats, gamma, beta, b, invC, tid);
    __syncthreads();

    int r2[CA], c2[CA], la[CA], g4[CA], pr[CA];
#pragma unroll
    for (int r = 0; r < CA; ++r) {
        int i = tid + r * 256;
        r2[r] = -1000; c2[r] = 0; la[r] = 0; g4[r] = 0; pr[r] = 0;
        if (i < AITER) {
            int tr = i / (IW * 4); int rem = i - tr * (IW * 4);
            int p = rem >> 2, part = rem & 3;
            r2[r] = 2 * (h0 - 1 + tr);
            c2[r] = 2 * (p - 1);
            la[r] = (tr * IW + p) * PAD + part * 8;
            g4[r] = part * 8;
            pr[r] = part;
        }
    }
    int gb[CB], lb[CB];
#pragma unroll
    for (int r = 0; r < CB; ++r) {
        int i = tid + r * 256;
        int tap = i >> 8, co = (i >> 2) & 63, part = i & 3;
        gb[r] = (tap * 128 + n0 + co) * 32 + part * 8;
        lb[r] = (tap * NT + co) * PAD + part * 8;
    }

    f32x4 acc[4][NF];
#pragma unroll
    for (int mf = 0; mf < 4; ++mf)
#pragma unroll
        for (int nf = 0; nf < NF; ++nf)
            acc[mf][nf] = (f32x4){0.f, 0.f, 0.f, 0.f};

    const ushort_t* ibase = in + (size_t)b * 128 * 128 * 64;
    uint4 ra[CA], rb[CB];

    auto loadA = [&](int cib) {
        const int p = cib >> 2, q = (cib >> 1) & 1, ch32 = (cib & 1) * 32;
#pragma unroll
        for (int r = 0; r < CA; ++r) {
            int ih = r2[r] + p, iw = c2[r] + q;
            uint4 v = make_uint4(0, 0, 0, 0);
            if ((unsigned)ih < 128u && (unsigned)iw < 128u) {
                v = *(const uint4*)(ibase + ((ih << 7) + iw) * 64 + ch32 + g4[r]);
                v = gn8(v, &sshare[ch32 + pr[r] * 8]);
            }
            ra[r] = v;
        }
    };
    auto loadB = [&](int cib) {
        const ushort_t* wb = wp + (size_t)cib * 4 * 128 * 32;
#pragma unroll
        for (int r = 0; r < CB; ++r)
            rb[r] = *(const uint4*)(wb + gb[r]);
    };

    loadA(0); loadB(0);

#pragma unroll
    for (int cib = 0; cib < 8; ++cib) {
        const int p = cib >> 2, q = (cib >> 1) & 1;
        __syncthreads();
#pragma unroll
        for (int r = 0; r < CA; ++r)
            if (tid + r * 256 < AITER) *(uint4*)&lA[la[r]] = ra[r];
#pragma unroll
        for (int r = 0; r < CB; ++r) *(uint4*)&lB[lb[r]] = rb[r];
        __syncthreads();
        if (cib + 1 < 8) { loadA(cib + 1); loadB(cib + 1); }

#pragma unroll
        for (int kh = 0; kh < 2; ++kh)
#pragma unroll
            for (int kw = 0; kw < 2; ++kw)
                if ((kh == 1 || p == 1) && (kw == 1 || q == 1)) {
                    short8 af[4];
#pragma unroll
                    for (int mf = 0; mf < 4; ++mf)
                        af[mf] = *(const short8*)&lA[((wid + kh) * IW + mf * 16 + nl + kw) * PAD + ql];
                    short8 bf[NF];
#pragma unroll
                    for (int nf = 0; nf < NF; ++nf)
                        bf[nf] = *(const short8*)&lB[((kh * 2 + kw) * NT + nf * 16 + nl) * PAD + ql];
#pragma unroll
                    for (int mf = 0; mf < 4; ++mf)
#pragma unroll
                        for (int nf = 0; nf < NF; ++nf)
                            acc[mf][nf] = __builtin_amdgcn_mfma_f32_16x16x32_bf16(
                                af[mf], bf[nf], acc[mf][nf], 0, 0, 0);
                }
    }

    float bs[NF];
#pragma unroll
    for (int nf = 0; nf < NF; ++nf) bs[nf] = bias[n0 + nf * 16 + nl];
#pragma unroll
    for (int nf = 0; nf < NF; ++nf) {
        float s = 0.f, ss = 0.f;
#pragma unroll
        for (int mf = 0; mf < 4; ++mf)
#pragma unroll
            for (int rg = 0; rg < 4; ++rg) {
                float v = acc[mf][nf][rg] + bs[nf];
                s += v; ss += v * v;
            }
        red_stats(s, ss);
        if (quad == 0 && (nl & 7) == 0) sred[wid][nf * 2 + (nl >> 3)] = make_float2(s, ss);
    }

    __syncthreads();
#pragma unroll
    for (int mf = 0; mf < 4; ++mf)
#pragma unroll
        for (int nf = 0; nf < NF; ++nf)
#pragma unroll
            for (int rg = 0; rg < 4; ++rg) {
                int px = wid * 64 + mf * 16 + quad * 4 + rg;
                lE[px * EP + nf * 16 + nl] = f2bf(acc[mf][nf][rg] + bs[nf]);
            }
    __syncthreads();
#pragma unroll
    for (int it = 0; it < 8; ++it) {
        int idx = it * 256 + tid;
        int px = idx >> 3, ck = idx & 7;
        int row = px >> 6, col = px & 63;
        uint4 v = *(const uint4*)&lE[px * EP + ck * 8];
        *(uint4*)(outp + (((size_t)b * 64 + h0 + row) * 64 + col) * 128 + n0 + ck * 8) = v;
    }
    if (tid < 8) {
        float2 t0 = sred[0][tid], t1 = sred[1][tid], t2 = sred[2][tid], t3 = sred[3][tid];
        float2* slot = &stats[(size_t)b * 16 + (n0 >> 3) + tid];
        atomicAdd(&slot->x, t0.x + t1.x + t2.x + t3.x);
        atomicAdd(&slot->y, t0.y + t1.y + t2.y + t3.y);
    }
}

// ---------------------------------------------------------------------------
// ConvTranspose 4x4 s2 p1 (input GN4 fused), 4 output-parity phases.
// in A4 raw [16,64,64,128] -> out A5 raw [16,128,128,64]
// ---------------------------------------------------------------------------
__global__ __launch_bounds__(256, 2) void convt_mfma(const ushort_t* __restrict__ in,
                                                     const ushort_t* __restrict__ wp,
                                                     const float* __restrict__ bias,
                                                     ushort_t* __restrict__ outp,
                                                     float2* __restrict__ stats,
                                                     const float2* __restrict__ instats,
                                                     const float* __restrict__ gamma,
                                                     const float* __restrict__ beta,
                                                     float invC) {
    constexpr int CIN = 128, COUT = 64, NT = 64, NF = 4;
    constexpr int IW = 66, NRI = 5;
    constexpr int AITER = NRI * IW * 4;
    constexpr int CA = 6, CB = 4;
    constexpr int EP = NT + 8;
    __shared__ ushort_t smem[NRI * IW * PAD + 4 * NT * PAD];
    __shared__ float2 sred[4][8];
    __shared__ float2 sshare[CIN];
    ushort_t* lA = smem;
    ushort_t* lB = smem + NRI * IW * PAD;
    ushort_t* lE = smem;

    int bid = blockIdx.x;
    int ht = bid & 15; bid >>= 4;
    int ph = bid & 3;
    int b  = bid >> 2;
    int eh = ph >> 1, ew = ph & 1;
    int ho0 = ht * 4;
    int tid = threadIdx.x;
    int lane = tid & 63, wid = tid >> 6;
    int nl = lane & 15, quad = lane >> 4, ql = quad * 8;

    fill_ss<CIN>(sshare, instats, gamma, beta, b, invC, tid);
    __syncthreads();

    int ga[CA], la[CA], pr[CA];
#pragma unroll
    for (int r = 0; r < CA; ++r) {
        int i = tid + r * 256;
        ga[r] = -1; la[r] = 0; pr[r] = 0;
        if (i < AITER) {
            int tr = i / (IW * 4); int rem = i - tr * (IW * 4);
            int p = rem >> 2, part = rem & 3;
            la[r] = (tr * IW + p) * PAD + part * 8;
            pr[r] = part;
            int ih = ho0 + tr - (1 - eh), iw = p - 1;
            if ((unsigned)ih < 64u && (unsigned)iw < 64u)
                ga[r] = (ih * 64 + iw) * CIN + part * 8;
        }
    }
    int gb[CB], lb[CB];
#pragma unroll
    for (int r = 0; r < CB; ++r) {
        int i = tid + r * 256;
        int tap = i >> 8, co = (i >> 2) & 63, part = i & 3;
        gb[r] = (tap * COUT + co) * 32 + part * 8;
        lb[r] = (tap * NT + co) * PAD + part * 8;
    }

    f32x4 acc[4][NF];
#pragma unroll
    for (int mf = 0; mf < 4; ++mf)
#pragma unroll
        for (int nf = 0; nf < NF; ++nf)
            acc[mf][nf] = (f32x4){0.f, 0.f, 0.f, 0.f};

    const ushort_t* ibase = in + (size_t)b * 64 * 64 * CIN;
    uint4 ra[CA], rb[CB];

    auto loadA = [&](int cib) {
#pragma unroll
        for (int r = 0; r < CA; ++r) {
            uint4 v = make_uint4(0, 0, 0, 0);
            if (ga[r] >= 0) {
                v = *(const uint4*)(ibase + ga[r] + cib * 32);
                v = gn8(v, &sshare[cib * 32 + pr[r] * 8]);
            }
            ra[r] = v;
        }
    };
    auto loadB = [&](int cib) {
        const ushort_t* wb = wp + ((size_t)ph * 4 + cib) * 4 * COUT * 32;
#pragma unroll
        for (int r = 0; r < CB; ++r)
            rb[r] = *(const uint4*)(wb + gb[r]);
    };

    loadA(0); loadB(0);

    for (int cib = 0; cib < 4; ++cib) {
        __syncthreads();
#pragma unroll
        for (int r = 0; r < CA; ++r)
            if (tid + r * 256 < AITER) *(uint4*)&lA[la[r]] = ra[r];
#pragma unroll
        for (int r = 0; r < CB; ++r) *(uint4*)&lB[lb[r]] = rb[r];
        __syncthreads();
        if (cib + 1 < 4) { loadA(cib + 1); loadB(cib + 1); }

#pragma unroll
        for (int tap = 0; tap < 4; ++tap) {
            const int rs = tap >> 1, cs = tap & 1;
            short8 af[4];
#pragma unroll
            for (int mf = 0; mf < 4; ++mf)
                af[mf] = *(const short8*)&lA[((wid + rs) * IW + mf * 16 + nl + cs + ew) * PAD + ql];
            short8 bf[NF];
#pragma unroll
            for (int nf = 0; nf < NF; ++nf)
                bf[nf] = *(const short8*)&lB[(tap * NT + nf * 16 + nl) * PAD + ql];
#pragma unroll
            for (int mf = 0; mf < 4; ++mf)
#pragma unroll
                for (int nf = 0; nf < NF; ++nf)
                    acc[mf][nf] = __builtin_amdgcn_mfma_f32_16x16x32_bf16(
                        af[mf], bf[nf], acc[mf][nf], 0, 0, 0);
        }
    }

    float bs[NF];
#pragma unroll
    for (int nf = 0; nf < NF; ++nf) bs[nf] = bias[nf * 16 + nl];
#pragma unroll
    for (int nf = 0; nf < NF; ++nf) {
        float s = 0.f, ss = 0.f;
#pragma unroll
        for (int mf = 0; mf < 4; ++mf)
#pragma unroll
            for (int rg = 0; rg < 4; ++rg) {
                float v = acc[mf][nf][rg] + bs[nf];
                s += v; ss += v * v;
            }
        red_stats(s, ss);
        if (quad == 0 && (nl & 7) == 0) sred[wid][nf * 2 + (nl >> 3)] = make_float2(s, ss);
    }

    __syncthreads();
#pragma unroll
    for (int mf = 0; mf < 4; ++mf)
#pragma unroll
        for (int nf = 0; nf < NF; ++nf)
#pragma unroll
            for (int rg = 0; rg < 4; ++rg) {
                int px = wid * 64 + mf * 16 + quad * 4 + rg;   // px = row*64 + wo
                lE[px * EP + nf * 16 + nl] = f2bf(acc[mf][nf][rg] + bs[nf]);
            }
    __syncthreads();
#pragma unroll
    for (int it = 0; it < 8; ++it) {
        int idx = it * 256 + tid;
        int px = idx >> 3, ck = idx & 7;
        int row = px >> 6, wo = px & 63;
        int oh = 2 * (ho0 + row) + eh;
        uint4 v = *(const uint4*)&lE[px * EP + ck * 8];
        *(uint4*)(outp + (((size_t)b * 128 + oh) * 128 + 2 * wo + ew) * 64 + ck * 8) = v;
    }
    if (tid < 8) {
        float2 t0 = sred[0][tid], t1 = sred[1][tid], t2 = sred[2][tid], t3 = sred[3][tid];
        float2* slot = &stats[(size_t)b * 8 + tid];
        atomicAdd(&slot->x, t0.x + t1.x + t2.x + t3.x);
        atomicAdd(&slot->y, t0.y + t1.y + t2.y + t3.y);
    }
}

// ---------------------------------------------------------------------------
extern "C" void kernel_launch(void* const* d_in, const int* in_sizes, int n_in,
                              void* d_out, int out_size, void* d_ws, size_t ws_size,
                              hipStream_t stream) {
    const float* x   = (const float*)d_in[0];
    const float* Kd  = (const float*)d_in[1];
    const float* Kr  = (const float*)d_in[2];
    const float* W1  = (const float*)d_in[3];  const float* b1  = (const float*)d_in[4];
    const float* g1  = (const float*)d_in[5];  const float* be1 = (const float*)d_in[6];
    const float* W2  = (const float*)d_in[7];  const float* b2  = (const float*)d_in[8];
    const float* g2  = (const float*)d_in[9];  const float* be2 = (const float*)d_in[10];
    const float* W3  = (const float*)d_in[11]; const float* b3  = (const float*)d_in[12];
    const float* g3  = (const float*)d_in[13]; const float* be3 = (const float*)d_in[14];
    const float* W4  = (const float*)d_in[15]; const float* b4  = (const float*)d_in[16];
    const float* g4  = (const float*)d_in[17]; const float* be4 = (const float*)d_in[18];
    const float* Wt  = (const float*)d_in[19]; const float* bt  = (const float*)d_in[20];
    const float* g5  = (const float*)d_in[21]; const float* be5 = (const float*)d_in[22];
    const float* W6  = (const float*)d_in[23]; const float* b6  = (const float*)d_in[24];

    ushort_t* U  = (ushort_t*)d_ws;
    ushort_t* V  = U + 8388608;
    ushort_t* WP = V + 16777216;
    ushort_t* wp1 = WP;
    ushort_t* wp2 = WP + 18432;
    ushort_t* wp3 = WP + 149504;
    ushort_t* wp4 = WP + 444416;
    ushort_t* wpt = WP + 739328;
    ushort_t* wp6 = WP + 870400;
    float2* stats = (float2*)(WP + 879616);
    float* out = (float*)d_out;

    hipMemsetAsync(stats, 0, 1280 * sizeof(float2), stream);
    pack_all<<<3436, 256, 0, stream>>>(W1, W2, W3, W4, Wt, W6, WP);

    // DWT: x -> U (A0 [16,128,128,32])
    dwt_nhwc<<<1024, 256, 0, stream>>>(x, Kd, U);

    // conv1 32->64 @128x128: U -> V (raw), stats s1
    conv_mfma<32, 64, 128, 128, true, false>
        <<<1024, 256, 0, stream>>>(U, wp1, b1, V, stats + 0, nullptr, nullptr, nullptr, 0.f);

    // conv2 (parity, GN1 in) 64->128 s2: V -> U, stats s2
    conv2p_mfma<<<512, 256, 0, stream>>>(V, wp2, b2, U, stats + 128,
                                         stats + 0, g1, be1, 1.f / 131072.f);

    // conv3 (GN2 in) 128->256 @64x64: U -> V, stats s3
    conv_mfma<128, 256, 64, 64, true, true>
        <<<1024, 256, 0, stream>>>(U, wp3, b3, V, stats + 384,
                                   stats + 128, g2, be2, 1.f / 32768.f);

    // conv4 (GN3 in) 256->128 @64x64: V -> U, stats s4
    conv_mfma<256, 128, 64, 64, true, true>
        <<<512, 256, 0, stream>>>(V, wp4, b4, U, stats + 896,
                                  stats + 384, g3, be3, 1.f / 32768.f);

    // convT (GN4 in) 128->64 x2: U -> V, stats s5
    convt_mfma<<<1024, 256, 0, stream>>>(U, wpt, bt, V, stats + 1152,
                                         stats + 896, g4, be4, 1.f / 32768.f);

    // conv6 (GN5 in) 64->16 @128x128: V -> U (bf16 [16,128,128,16])
    conv_mfma<64, 16, 128, 128, false, true>
        <<<1024, 256, 0, stream>>>(V, wp6, b6, U, nullptr,
                                   stats + 1152, g5, be5, 1.f / 131072.f);

    // IDWT: U -> out
    idwt_nhwc<<<1024, 256, 0, stream>>>(U, Kr, out);
}

// Round 6
// 446.360 us; speedup vs baseline: 17.8130x; 1.1249x over previous
//
#include <hip/hip_runtime.h>

typedef unsigned short ushort_t;
typedef unsigned int uint_t;
typedef __attribute__((ext_vector_type(8))) short short8;
typedef __attribute__((ext_vector_type(4))) float f32x4;

#define PAD 40   // staging LDS elems per pixel/co row: bank stride 20 -> 2-way (free)

__device__ __forceinline__ ushort_t f2bf(float f) {
    uint_t u = __float_as_uint(f);
    u = (u + 0x7FFFu + ((u >> 16) & 1u)) >> 16;
    return (ushort_t)u;
}
__device__ __forceinline__ float bf2f(ushort_t h) {
    return __uint_as_float(((uint_t)h) << 16);
}

__device__ __forceinline__ void red_stats(float& s, float& ss) {
    s += __shfl_xor(s, 16); ss += __shfl_xor(ss, 16);
    s += __shfl_xor(s, 32); ss += __shfl_xor(ss, 32);
    s += __shfl_xor(s, 1);  ss += __shfl_xor(ss, 1);
    s += __shfl_xor(s, 2);  ss += __shfl_xor(ss, 2);
    s += __shfl_xor(s, 4);  ss += __shfl_xor(ss, 4);
}

// normalize 8 bf16 channels with (scale,shift) from LDS table + ReLU
__device__ __forceinline__ uint4 gn8(uint4 v, const float2* ss) {
    uint_t u[4] = {v.x, v.y, v.z, v.w};
    uint_t r[4];
#pragma unroll
    for (int p = 0; p < 4; ++p) {
        float2 s0 = ss[2 * p], s1 = ss[2 * p + 1];
        float f0 = fmaxf(bf2f((ushort_t)(u[p] & 0xffffu)) * s0.x + s0.y, 0.f);
        float f1 = fmaxf(bf2f((ushort_t)(u[p] >> 16)) * s1.x + s1.y, 0.f);
        r[p] = (uint_t)f2bf(f0) | ((uint_t)f2bf(f1) << 16);
    }
    return make_uint4(r[0], r[1], r[2], r[3]);
}

// fill per-channel (scale, shift) LDS table from per-block partial (sum, sumsq)
// stats. Deterministic fixed-order reduction over NPB partials.
template<int C, int NPB>
__device__ __forceinline__ void fill_ss(float2* sshare, const float2* __restrict__ pin,
                                        const float* __restrict__ gamma,
                                        const float* __restrict__ beta,
                                        int b, float invC, int tid) {
    for (int c = tid; c < C; c += 256) {
        const float2* p = pin + ((size_t)b * (C / 8) + (c >> 3)) * NPB;
        float s = 0.f, ss = 0.f;
#pragma unroll 8
        for (int i = 0; i < NPB; ++i) { s += p[i].x; ss += p[i].y; }
        float mean = s * invC;
        float rstd = rsqrtf(ss * invC - mean * mean + 1e-5f);
        float sc = gamma[c] * rstd;
        sshare[c] = make_float2(sc, beta[c] - mean * sc);
    }
}

// ---------------------------------------------------------------------------
// Weight packing (one merged kernel)
// ---------------------------------------------------------------------------
template<int CIN, int COUT>
__device__ __forceinline__ void pack3(const float* __restrict__ W, ushort_t* __restrict__ wp, int idx) {
    int kk = idx & 31;
    int t = idx >> 5;
    int co = t % COUT; t /= COUT;
    int tap = t % 9;
    int cib = t / 9;
    wp[idx] = f2bf(W[(co * CIN + cib * 32 + kk) * 9 + tap]);
}

__device__ __forceinline__ void pack2p(const float* __restrict__ W2, ushort_t* __restrict__ wp, int idx) {
    int kk = idx & 31;
    int co = (idx >> 5) & 127;
    int tap = (idx >> 12) & 3;
    int cib = idx >> 14;
    int p = cib >> 2, q = (cib >> 1) & 1, chalf = cib & 1;
    int kh = 2 * (tap >> 1) + p - 1;
    int kw = 2 * (tap & 1) + q - 1;
    float v = 0.f;
    if (kh >= 0 && kh < 3 && kw >= 0 && kw < 3)
        v = W2[(co * 64 + chalf * 32 + kk) * 9 + kh * 3 + kw];
    wp[idx] = f2bf(v);
}

__device__ __forceinline__ void packt(const float* __restrict__ Wt, ushort_t* __restrict__ wp, int idx) {
    int kk = idx & 31;
    int t = idx >> 5;
    int co = t & 63; t >>= 6;
    int tap = t & 3; t >>= 2;
    int cib = t & 3;
    int ph = t >> 2;
    int rs = tap >> 1, cs = tap & 1;
    int eh = ph >> 1, ew = ph & 1;
    int kh = eh ? (rs ? 0 : 2) : (rs ? 1 : 3);
    int kw = ew ? (cs ? 0 : 2) : (cs ? 1 : 3);
    wp[idx] = f2bf(Wt[((cib * 32 + kk) * 64 + co) * 16 + kh * 4 + kw]);
}

__global__ __launch_bounds__(256) void pack_all(const float* __restrict__ W1,
                                                const float* __restrict__ W2,
                                                const float* __restrict__ W3,
                                                const float* __restrict__ W4,
                                                const float* __restrict__ Wt,
                                                const float* __restrict__ W6,
                                                ushort_t* __restrict__ WP) {
    int idx = blockIdx.x * 256 + threadIdx.x;
    if (idx < 18432)        pack3<32, 64>(W1, WP, idx);
    else if (idx < 149504)  pack2p(W2, WP + 18432, idx - 18432);
    else if (idx < 444416)  pack3<128, 256>(W3, WP + 149504, idx - 149504);
    else if (idx < 739328)  pack3<256, 128>(W4, WP + 444416, idx - 444416);
    else if (idx < 870400)  packt(Wt, WP + 739328, idx - 739328);
    else if (idx < 879616)  pack3<64, 16>(W6, WP + 870400, idx - 870400);
}

// ---------------------------------------------------------------------------
// DWT: x NCHW fp32 [16,8,256,256] -> NHWC bf16 [16,128,128,32]
// ---------------------------------------------------------------------------
__global__ __launch_bounds__(256) void dwt_nhwc(const float* __restrict__ x,
                                                const float* __restrict__ Kd,
                                                ushort_t* __restrict__ out) {
    int idx = blockIdx.x * 256 + threadIdx.x;
    int w = idx & 127, h = (idx >> 7) & 127, b = idx >> 14;
    float k[16];
#pragma unroll
    for (int i = 0; i < 16; ++i) k[i] = Kd[i];
    const float* xb = x + (size_t)b * 8 * 65536;
    uint_t uu[16];
#pragma unroll
    for (int ci = 0; ci < 8; ++ci) {
        const float* p = xb + ci * 65536 + (2 * h) * 256 + 2 * w;
        float2 r0 = *(const float2*)p;
        float2 r1 = *(const float2*)(p + 256);
        ushort_t o[4];
#pragma unroll
        for (int sb = 0; sb < 4; ++sb) {
            float v = r0.x * k[sb*4] + r0.y * k[sb*4+1] + r1.x * k[sb*4+2] + r1.y * k[sb*4+3];
            o[sb] = f2bf(v);
        }
        uu[ci*2]   = (uint_t)o[0] | ((uint_t)o[1] << 16);
        uu[ci*2+1] = (uint_t)o[2] | ((uint_t)o[3] << 16);
    }
    uint4* dst = (uint4*)(out + (size_t)idx * 32);
    dst[0] = make_uint4(uu[0], uu[1], uu[2], uu[3]);
    dst[1] = make_uint4(uu[4], uu[5], uu[6], uu[7]);
    dst[2] = make_uint4(uu[8], uu[9], uu[10], uu[11]);
    dst[3] = make_uint4(uu[12], uu[13], uu[14], uu[15]);
}

// ---------------------------------------------------------------------------
// IDWT: in NHWC bf16 [16,128,128,16] -> out NCHW fp32 [16,4,256,256]
// ---------------------------------------------------------------------------
__global__ __launch_bounds__(256) void idwt_nhwc(const ushort_t* __restrict__ cin,
                                                 const float* __restrict__ Kr,
                                                 float* __restrict__ out) {
    int idx = blockIdx.x * 256 + threadIdx.x;
    int w = idx & 127, h = (idx >> 7) & 127, b = idx >> 14;
    float k[16];
#pragma unroll
    for (int i = 0; i < 16; ++i) k[i] = Kr[i];
    const uint4* pv = (const uint4*)(cin + (size_t)idx * 16);
    uint4 v0 = pv[0], v1 = pv[1];
    uint_t uw[8] = {v0.x, v0.y, v0.z, v0.w, v1.x, v1.y, v1.z, v1.w};
    float cs[16];
#pragma unroll
    for (int i = 0; i < 8; ++i) {
        cs[2*i]   = bf2f((ushort_t)(uw[i] & 0xffffu));
        cs[2*i+1] = bf2f((ushort_t)(uw[i] >> 16));
    }
#pragma unroll
    for (int c = 0; c < 4; ++c) {
        float y00 = 0, y01 = 0, y10 = 0, y11 = 0;
#pragma unroll
        for (int sb = 0; sb < 4; ++sb) {
            float v = cs[c * 4 + sb];
            y00 += v * k[sb*4];   y01 += v * k[sb*4+1];
            y10 += v * k[sb*4+2]; y11 += v * k[sb*4+3];
        }
        float* ob = out + ((size_t)(b * 4 + c) * 256 + 2 * h) * 256 + 2 * w;
        *(float2*)ob = make_float2(y00, y01);
        *(float2*)(ob + 256) = make_float2(y10, y11);
    }
}

// ---------------------------------------------------------------------------
// Implicit-GEMM 3x3 stride-1 conv, NHWC bf16, MFMA 16x16x32.
// XCD-swizzled grid; deterministic partial-stats output (no atomics).
// ---------------------------------------------------------------------------
template<int CIN, int COUT, int H, int W, bool STATS, bool GNIN, int NPBI>
__global__ __launch_bounds__(256, 2) void conv_mfma(const ushort_t* __restrict__ in,
                                                    const ushort_t* __restrict__ wp,
                                                    const float* __restrict__ bias,
                                                    ushort_t* __restrict__ outp,
                                                    float2* __restrict__ pstats_out,
                                                    const float2* __restrict__ pstats_in,
                                                    const float* __restrict__ gamma,
                                                    const float* __restrict__ beta,
                                                    float invC) {
    constexpr int NT = (COUT < 64) ? COUT : 64;
    constexpr int NF = NT / 16;
    constexpr int NCB = CIN / 32;
    constexpr int IW = 66, NRI = 6;
    constexpr int AITER = NRI * IW * 4;
    constexpr int CA = (AITER + 255) / 256;
    constexpr int BITER = 9 * NT * 4;
    constexpr int CB = (BITER + 255) / 256;
    constexpr int NB = COUT / NT, NW = W / 64, NH = H / 4;
    constexpr int PB = NB * NW * NH;
    constexpr int NPBO = NH * NW;                 // partials per (b, group)
    constexpr int EP = NT + 8;

    __shared__ ushort_t smem[NRI * IW * PAD + 9 * NT * PAD];
    __shared__ float2 sred[4][8];
    __shared__ float2 sshare[CIN];
    ushort_t* lA = smem;
    ushort_t* lB = smem + NRI * IW * PAD;
    ushort_t* lE = smem;

    // XCD-locality decode: xcd = bid&7 -> batch group {xcd, xcd+8}
    int bid = blockIdx.x;
    int xcd = bid & 7;
    int rest = bid >> 3;
    int half = rest / PB;
    int local = rest - half * PB;
    int b = xcd + 8 * half;
    int ht = local % NH; local /= NH;
    int wt = local % NW; local /= NW;
    int nb = local;
    int h0 = ht * 4, w0 = wt * 64, n0 = nb * NT;
    int tid = threadIdx.x;
    int lane = tid & 63, wid = tid >> 6;
    int nl = lane & 15, quad = lane >> 4, ql = quad * 8;

    if (GNIN) {
        fill_ss<CIN, NPBI>(sshare, pstats_in, gamma, beta, b, invC, tid);
        __syncthreads();
    }

    int ga[CA], la[CA], pr[CA];
#pragma unroll
    for (int r = 0; r < CA; ++r) {
        int i = tid + r * 256;
        ga[r] = -1; la[r] = 0; pr[r] = 0;
        if (i < AITER) {
            int tr = i / (IW * 4); int rem = i - tr * (IW * 4);
            int p = rem >> 2, part = rem & 3;
            la[r] = (tr * IW + p) * PAD + part * 8;
            pr[r] = part;
            int ih = h0 - 1 + tr, iw = w0 - 1 + p;
            if ((unsigned)ih < (unsigned)H && (unsigned)iw < (unsigned)W)
                ga[r] = (ih * W + iw) * CIN + part * 8;
        }
    }
    int gb[CB], lb[CB];
#pragma unroll
    for (int r = 0; r < CB; ++r) {
        int i = tid + r * 256;
        gb[r] = -1; lb[r] = 0;
        if (i < BITER) {
            int tap = i / (NT * 4); int rem = i - tap * (NT * 4);
            int co = rem >> 2, part = rem & 3;
            gb[r] = (tap * COUT + n0 + co) * 32 + part * 8;
            lb[r] = (tap * NT + co) * PAD + part * 8;
        }
    }

    f32x4 acc[4][NF];
#pragma unroll
    for (int mf = 0; mf < 4; ++mf)
#pragma unroll
        for (int nf = 0; nf < NF; ++nf)
            acc[mf][nf] = (f32x4){0.f, 0.f, 0.f, 0.f};

    const ushort_t* ibase = in + (size_t)b * H * W * CIN;
    uint4 ra[CA], rb[CB];

    auto loadA = [&](int cib) {
#pragma unroll
        for (int r = 0; r < CA; ++r) {
            uint4 v = make_uint4(0, 0, 0, 0);
            if (ga[r] >= 0) {
                v = *(const uint4*)(ibase + ga[r] + cib * 32);
                if (GNIN) v = gn8(v, &sshare[cib * 32 + pr[r] * 8]);
            }
            ra[r] = v;
        }
    };
    auto loadB = [&](int cib) {
        const ushort_t* wb = wp + (size_t)cib * 9 * COUT * 32;
#pragma unroll
        for (int r = 0; r < CB; ++r)
            if (gb[r] >= 0) rb[r] = *(const uint4*)(wb + gb[r]);
    };

    loadA(0); loadB(0);

    for (int cib = 0; cib < NCB; ++cib) {
        __syncthreads();
#pragma unroll
        for (int r = 0; r < CA; ++r)
            if (tid + r * 256 < AITER) *(uint4*)&lA[la[r]] = ra[r];
#pragma unroll
        for (int r = 0; r < CB; ++r)
            if (tid + r * 256 < BITER) *(uint4*)&lB[lb[r]] = rb[r];
        __syncthreads();
        if (cib + 1 < NCB) { loadA(cib + 1); loadB(cib + 1); }

#pragma unroll
        for (int tap = 0; tap < 9; ++tap) {
            const int kh = tap / 3, kw = tap % 3;
            short8 af[4];
#pragma unroll
            for (int mf = 0; mf < 4; ++mf)
                af[mf] = *(const short8*)&lA[((wid + kh) * IW + mf * 16 + nl + kw) * PAD + ql];
            short8 bf[NF];
#pragma unroll
            for (int nf = 0; nf < NF; ++nf)
                bf[nf] = *(const short8*)&lB[(tap * NT + nf * 16 + nl) * PAD + ql];
#pragma unroll
            for (int mf = 0; mf < 4; ++mf)
#pragma unroll
                for (int nf = 0; nf < NF; ++nf)
                    acc[mf][nf] = __builtin_amdgcn_mfma_f32_16x16x32_bf16(
                        af[mf], bf[nf], acc[mf][nf], 0, 0, 0);
        }
    }

    float bs[NF];
#pragma unroll
    for (int nf = 0; nf < NF; ++nf) bs[nf] = bias[n0 + nf * 16 + nl];

    if (STATS) {
#pragma unroll
        for (int nf = 0; nf < NF; ++nf) {
            float s = 0.f, ss = 0.f;
#pragma unroll
            for (int mf = 0; mf < 4; ++mf)
#pragma unroll
                for (int rg = 0; rg < 4; ++rg) {
                    float v = acc[mf][nf][rg] + bs[nf];
                    s += v; ss += v * v;
                }
            red_stats(s, ss);
            if (quad == 0 && (nl & 7) == 0) sred[wid][nf * 2 + (nl >> 3)] = make_float2(s, ss);
        }
    }

    __syncthreads();
#pragma unroll
    for (int mf = 0; mf < 4; ++mf)
#pragma unroll
        for (int nf = 0; nf < NF; ++nf)
#pragma unroll
            for (int rg = 0; rg < 4; ++rg) {
                int px = wid * 64 + mf * 16 + quad * 4 + rg;
                lE[px * EP + nf * 16 + nl] = f2bf(acc[mf][nf][rg] + bs[nf]);
            }
    __syncthreads();
#pragma unroll
    for (int it = 0; it < NT / 8; ++it) {
        int idx = it * 256 + tid;
        int px = idx / (NT / 8), ck = idx % (NT / 8);
        int row = px >> 6, col = px & 63;
        uint4 v = *(const uint4*)&lE[px * EP + ck * 8];
        *(uint4*)(outp + (((size_t)b * H + h0 + row) * W + w0 + col) * COUT + n0 + ck * 8) = v;
    }
    if (STATS && tid < 2 * NF) {
        float2 t0 = sred[0][tid], t1 = sred[1][tid], t2 = sred[2][tid], t3 = sred[3][tid];
        pstats_out[((size_t)b * (COUT / 8) + (n0 >> 3) + tid) * NPBO + (ht * NW + wt)] =
            make_float2(t0.x + t1.x + t2.x + t3.x, t0.y + t1.y + t2.y + t3.y);
    }
}

// ---------------------------------------------------------------------------
// conv2 (3x3 stride-2) as dense parity conv (input GN1 fused), XCD-swizzled.
// in A1 raw [16,128,128,64] bf16 -> out A2 raw [16,64,64,128] bf16
// ---------------------------------------------------------------------------
__global__ __launch_bounds__(256, 2) void conv2p_mfma(const ushort_t* __restrict__ in,
                                                      const ushort_t* __restrict__ wp,
                                                      const float* __restrict__ bias,
                                                      ushort_t* __restrict__ outp,
                                                      float2* __restrict__ pstats_out,
                                                      const float2* __restrict__ pstats_in,
                                                      const float* __restrict__ gamma,
                                                      const float* __restrict__ beta,
                                                      float invC) {
    constexpr int IW = 65, NRI = 5, NF = 4, NT = 64;
    constexpr int AITER = NRI * IW * 4;
    constexpr int CA = 6, CB = 4;
    constexpr int EP = NT + 8;
    __shared__ ushort_t smem[NRI * IW * PAD + 4 * NT * PAD];
    __shared__ float2 sred[4][8];
    __shared__ float2 sshare[64];
    ushort_t* lA = smem;
    ushort_t* lB = smem + NRI * IW * PAD;
    ushort_t* lE = smem;

    // grid 512 = 8 xcd * 2 half * 32 local(16 ht x 2 nb)
    int bid = blockIdx.x;
    int xcd = bid & 7;
    int rest = bid >> 3;
    int half = rest >> 5;
    int local = rest & 31;
    int b = xcd + 8 * half;
    int ht = local & 15;
    int nb = local >> 4;
    int h0 = ht * 4, n0 = nb * 64;
    int tid = threadIdx.x;
    int lane = tid & 63, wid = tid >> 6;
    int nl = lane & 15, quad = lane >> 4, ql = quad * 8;

    fill_ss<64, 64>(sshare, pstats_in, gamma, beta, b, invC, tid);
    __syncthreads();

    int r2[CA], c2[CA], la[CA], g4[CA], pr[CA];
#pragma unroll
    for (int r = 0; r < CA; ++r) {
        int i = tid + r * 256;
        r2[r] = -1000; c2[r] = 0; la[r] = 0; g4[r] = 0; pr[r] = 0;
        if (i < AITER) {
            int tr = i / (IW * 4); int rem = i - tr * (IW * 4);
            int p = rem >> 2, part = rem & 3;
            r2[r] = 2 * (h0 - 1 + tr);
            c2[r] = 2 * (p - 1);
            la[r] = (tr * IW + p) * PAD + part * 8;
            g4[r] = part * 8;
            pr[r] = part;
        }
    }
    int gb[CB], lb[CB];
#pragma unroll
    for (int r = 0; r < CB; ++r) {
        int i = tid + r * 256;
        int tap = i >> 8, co = (i >> 2) & 63, part = i & 3;
        gb[r] = (tap * 128 + n0 + co) * 32 + part * 8;
        lb[r] = (tap * NT + co) * PAD + part * 8;
    }

    f32x4 acc[4][NF];
#pragma unroll
    for (int mf = 0; mf < 4; ++mf)
#pragma unroll
        for (int nf = 0; nf < NF; ++nf)
            acc[mf][nf] = (f32x4){0.f, 0.f, 0.f, 0.f};

    const ushort_t* ibase = in + (size_t)b * 128 * 128 * 64;
    uint4 ra[CA], rb[CB];

    auto loadA = [&](int cib) {
        const int p = cib >> 2, q = (cib >> 1) & 1, ch32 = (cib & 1) * 32;
#pragma unroll
        for (int r = 0; r < CA; ++r) {
            int ih = r2[r] + p, iw = c2[r] + q;
            uint4 v = make_uint4(0, 0, 0, 0);
            if ((unsigned)ih < 128u && (unsigned)iw < 128u) {
                v = *(const uint4*)(ibase + ((ih << 7) + iw) * 64 + ch32 + g4[r]);
                v = gn8(v, &sshare[ch32 + pr[r] * 8]);
            }
            ra[r] = v;
        }
    };
    auto loadB = [&](int cib) {
        const ushort_t* wb = wp + (size_t)cib * 4 * 128 * 32;
#pragma unroll
        for (int r = 0; r < CB; ++r)
            rb[r] = *(const uint4*)(wb + gb[r]);
    };

    loadA(0); loadB(0);

#pragma unroll
    for (int cib = 0; cib < 8; ++cib) {
        const int p = cib >> 2, q = (cib >> 1) & 1;
        __syncthreads();
#pragma unroll
        for (int r = 0; r < CA; ++r)
            if (tid + r * 256 < AITER) *(uint4*)&lA[la[r]] = ra[r];
#pragma unroll
        for (int r = 0; r < CB; ++r) *(uint4*)&lB[lb[r]] = rb[r];
        __syncthreads();
        if (cib + 1 < 8) { loadA(cib + 1); loadB(cib + 1); }

#pragma unroll
        for (int kh = 0; kh < 2; ++kh)
#pragma unroll
            for (int kw = 0; kw < 2; ++kw)
                if ((kh == 1 || p == 1) && (kw == 1 || q == 1)) {
                    short8 af[4];
#pragma unroll
                    for (int mf = 0; mf < 4; ++mf)
                        af[mf] = *(const short8*)&lA[((wid + kh) * IW + mf * 16 + nl + kw) * PAD + ql];
                    short8 bf[NF];
#pragma unroll
                    for (int nf = 0; nf < NF; ++nf)
                        bf[nf] = *(const short8*)&lB[((kh * 2 + kw) * NT + nf * 16 + nl) * PAD + ql];
#pragma unroll
                    for (int mf = 0; mf < 4; ++mf)
#pragma unroll
                        for (int nf = 0; nf < NF; ++nf)
                            acc[mf][nf] = __builtin_amdgcn_mfma_f32_16x16x32_bf16(
                                af[mf], bf[nf], acc[mf][nf], 0, 0, 0);
                }
    }

    float bs[NF];
#pragma unroll
    for (int nf = 0; nf < NF; ++nf) bs[nf] = bias[n0 + nf * 16 + nl];
#pragma unroll
    for (int nf = 0; nf < NF; ++nf) {
        float s = 0.f, ss = 0.f;
#pragma unroll
        for (int mf = 0; mf < 4; ++mf)
#pragma unroll
            for (int rg = 0; rg < 4; ++rg) {
                float v = acc[mf][nf][rg] + bs[nf];
                s += v; ss += v * v;
            }
        red_stats(s, ss);
        if (quad == 0 && (nl & 7) == 0) sred[wid][nf * 2 + (nl >> 3)] = make_float2(s, ss);
    }

    __syncthreads();
#pragma unroll
    for (int mf = 0; mf < 4; ++mf)
#pragma unroll
        for (int nf = 0; nf < NF; ++nf)
#pragma unroll
            for (int rg = 0; rg < 4; ++rg) {
                int px = wid * 64 + mf * 16 + quad * 4 + rg;
                lE[px * EP + nf * 16 + nl] = f2bf(acc[mf][nf][rg] + bs[nf]);
            }
    __syncthreads();
#pragma unroll
    for (int it = 0; it < 8; ++it) {
        int idx = it * 256 + tid;
        int px = idx >> 3, ck = idx & 7;
        int row = px >> 6, col = px & 63;
        uint4 v = *(const uint4*)&lE[px * EP + ck * 8];
        *(uint4*)(outp + (((size_t)b * 64 + h0 + row) * 64 + col) * 128 + n0 + ck * 8) = v;
    }
    if (tid < 8) {
        float2 t0 = sred[0][tid], t1 = sred[1][tid], t2 = sred[2][tid], t3 = sred[3][tid];
        pstats_out[((size_t)b * 16 + (n0 >> 3) + tid) * 16 + ht] =
            make_float2(t0.x + t1.x + t2.x + t3.x, t0.y + t1.y + t2.y + t3.y);
    }
}

// ---------------------------------------------------------------------------
// ConvTranspose 4x4 s2 p1 (input GN4 fused), 4 output-parity phases, XCD-swizzled.
// in A4 raw [16,64,64,128] -> out A5 raw [16,128,128,64]
// ---------------------------------------------------------------------------
__global__ __launch_bounds__(256, 2) void convt_mfma(const ushort_t* __restrict__ in,
                                                     const ushort_t* __restrict__ wp,
                                                     const float* __restrict__ bias,
                                                     ushort_t* __restrict__ outp,
                                                     float2* __restrict__ pstats_out,
                                                     const float2* __restrict__ pstats_in,
                                                     const float* __restrict__ gamma,
                                                     const float* __restrict__ beta,
                                                     float invC) {
    constexpr int CIN = 128, COUT = 64, NT = 64, NF = 4;
    constexpr int IW = 66, NRI = 5;
    constexpr int AITER = NRI * IW * 4;
    constexpr int CA = 6, CB = 4;
    constexpr int EP = NT + 8;
    __shared__ ushort_t smem[NRI * IW * PAD + 4 * NT * PAD];
    __shared__ float2 sred[4][8];
    __shared__ float2 sshare[CIN];
    ushort_t* lA = smem;
    ushort_t* lB = smem + NRI * IW * PAD;
    ushort_t* lE = smem;

    // grid 1024 = 8 xcd * 2 half * 64 local(16 ht x 4 ph)
    int bid = blockIdx.x;
    int xcd = bid & 7;
    int rest = bid >> 3;
    int half = rest >> 6;
    int local = rest & 63;
    int b = xcd + 8 * half;
    int ht = local & 15;
    int ph = local >> 4;
    int eh = ph >> 1, ew = ph & 1;
    int ho0 = ht * 4;
    int tid = threadIdx.x;
    int lane = tid & 63, wid = tid >> 6;
    int nl = lane & 15, quad = lane >> 4, ql = quad * 8;

    fill_ss<CIN, 16>(sshare, pstats_in, gamma, beta, b, invC, tid);
    __syncthreads();

    int ga[CA], la[CA], pr[CA];
#pragma unroll
    for (int r = 0; r < CA; ++r) {
        int i = tid + r * 256;
        ga[r] = -1; la[r] = 0; pr[r] = 0;
        if (i < AITER) {
            int tr = i / (IW * 4); int rem = i - tr * (IW * 4);
            int p = rem >> 2, part = rem & 3;
            la[r] = (tr * IW + p) * PAD + part * 8;
            pr[r] = part;
            int ih = ho0 + tr - (1 - eh), iw = p - 1;
            if ((unsigned)ih < 64u && (unsigned)iw < 64u)
                ga[r] = (ih * 64 + iw) * CIN + part * 8;
        }
    }
    int gb[CB], lb[CB];
#pragma unroll
    for (int r = 0; r < CB; ++r) {
        int i = tid + r * 256;
        int tap = i >> 8, co = (i >> 2) & 63, part = i & 3;
        gb[r] = (tap * COUT + co) * 32 + part * 8;
        lb[r] = (tap * NT + co) * PAD + part * 8;
    }

    f32x4 acc[4][NF];
#pragma unroll
    for (int mf = 0; mf < 4; ++mf)
#pragma unroll
        for (int nf = 0; nf < NF; ++nf)
            acc[mf][nf] = (f32x4){0.f, 0.f, 0.f, 0.f};

    const ushort_t* ibase = in + (size_t)b * 64 * 64 * CIN;
    uint4 ra[CA], rb[CB];

    auto loadA = [&](int cib) {
#pragma unroll
        for (int r = 0; r < CA; ++r) {
            uint4 v = make_uint4(0, 0, 0, 0);
            if (ga[r] >= 0) {
                v = *(const uint4*)(ibase + ga[r] + cib * 32);
                v = gn8(v, &sshare[cib * 32 + pr[r] * 8]);
            }
            ra[r] = v;
        }
    };
    auto loadB = [&](int cib) {
        const ushort_t* wb = wp + ((size_t)ph * 4 + cib) * 4 * COUT * 32;
#pragma unroll
        for (int r = 0; r < CB; ++r)
            rb[r] = *(const uint4*)(wb + gb[r]);
    };

    loadA(0); loadB(0);

    for (int cib = 0; cib < 4; ++cib) {
        __syncthreads();
#pragma unroll
        for (int r = 0; r < CA; ++r)
            if (tid + r * 256 < AITER) *(uint4*)&lA[la[r]] = ra[r];
#pragma unroll
        for (int r = 0; r < CB; ++r) *(uint4*)&lB[lb[r]] = rb[r];
        __syncthreads();
        if (cib + 1 < 4) { loadA(cib + 1); loadB(cib + 1); }

#pragma unroll
        for (int tap = 0; tap < 4; ++tap) {
            const int rs = tap >> 1, cs = tap & 1;
            short8 af[4];
#pragma unroll
            for (int mf = 0; mf < 4; ++mf)
                af[mf] = *(const short8*)&lA[((wid + rs) * IW + mf * 16 + nl + cs + ew) * PAD + ql];
            short8 bf[NF];
#pragma unroll
            for (int nf = 0; nf < NF; ++nf)
                bf[nf] = *(const short8*)&lB[(tap * NT + nf * 16 + nl) * PAD + ql];
#pragma unroll
            for (int mf = 0; mf < 4; ++mf)
#pragma unroll
                for (int nf = 0; nf < NF; ++nf)
                    acc[mf][nf] = __builtin_amdgcn_mfma_f32_16x16x32_bf16(
                        af[mf], bf[nf], acc[mf][nf], 0, 0, 0);
        }
    }

    float bs[NF];
#pragma unroll
    for (int nf = 0; nf < NF; ++nf) bs[nf] = bias[nf * 16 + nl];
#pragma unroll
    for (int nf = 0; nf < NF; ++nf) {
        float s = 0.f, ss = 0.f;
#pragma unroll
        for (int mf = 0; mf < 4; ++mf)
#pragma unroll
            for (int rg = 0; rg < 4; ++rg) {
                float v = acc[mf][nf][rg] + bs[nf];
                s += v; ss += v * v;
            }
        red_stats(s, ss);
        if (quad == 0 && (nl & 7) == 0) sred[wid][nf * 2 + (nl >> 3)] = make_float2(s, ss);
    }

    __syncthreads();
#pragma unroll
    for (int mf = 0; mf < 4; ++mf)
#pragma unroll
        for (int nf = 0; nf < NF; ++nf)
#pragma unroll
            for (int rg = 0; rg < 4; ++rg) {
                int px = wid * 64 + mf * 16 + quad * 4 + rg;
                lE[px * EP + nf * 16 + nl] = f2bf(acc[mf][nf][rg] + bs[nf]);
            }
    __syncthreads();
#pragma unroll
    for (int it = 0; it < 8; ++it) {
        int idx = it * 256 + tid;
        int px = idx >> 3, ck = idx & 7;
        int row = px >> 6, wo = px & 63;
        int oh = 2 * (ho0 + row) + eh;
        uint4 v = *(const uint4*)&lE[px * EP + ck * 8];
        *(uint4*)(outp + (((size_t)b * 128 + oh) * 128 + 2 * wo + ew) * 64 + ck * 8) = v;
    }
    if (tid < 8) {
        float2 t0 = sred[0][tid], t1 = sred[1][tid], t2 = sred[2][tid], t3 = sred[3][tid];
        pstats_out[((size_t)b * 8 + tid) * 64 + (ht * 4 + ph)] =
            make_float2(t0.x + t1.x + t2.x + t3.x, t0.y + t1.y + t2.y + t3.y);
    }
}

// ---------------------------------------------------------------------------
extern "C" void kernel_launch(void* const* d_in, const int* in_sizes, int n_in,
                              void* d_out, int out_size, void* d_ws, size_t ws_size,
                              hipStream_t stream) {
    const float* x   = (const float*)d_in[0];
    const float* Kd  = (const float*)d_in[1];
    const float* Kr  = (const float*)d_in[2];
    const float* W1  = (const float*)d_in[3];  const float* b1  = (const float*)d_in[4];
    const float* g1  = (const float*)d_in[5];  const float* be1 = (const float*)d_in[6];
    const float* W2  = (const float*)d_in[7];  const float* b2  = (const float*)d_in[8];
    const float* g2  = (const float*)d_in[9];  const float* be2 = (const float*)d_in[10];
    const float* W3  = (const float*)d_in[11]; const float* b3  = (const float*)d_in[12];
    const float* g3  = (const float*)d_in[13]; const float* be3 = (const float*)d_in[14];
    const float* W4  = (const float*)d_in[15]; const float* b4  = (const float*)d_in[16];
    const float* g4  = (const float*)d_in[17]; const float* be4 = (const float*)d_in[18];
    const float* Wt  = (const float*)d_in[19]; const float* bt  = (const float*)d_in[20];
    const float* g5  = (const float*)d_in[21]; const float* be5 = (const float*)d_in[22];
    const float* W6  = (const float*)d_in[23]; const float* b6  = (const float*)d_in[24];

    ushort_t* U  = (ushort_t*)d_ws;
    ushort_t* V  = U + 8388608;
    ushort_t* WP = V + 16777216;
    ushort_t* wp1 = WP;
    ushort_t* wp2 = WP + 18432;
    ushort_t* wp3 = WP + 149504;
    ushort_t* wp4 = WP + 444416;
    ushort_t* wpt = WP + 739328;
    ushort_t* wp6 = WP + 870400;
    // per-block partial GN stats (fully rewritten each launch; no init needed)
    float2* PS = (float2*)(WP + 879616);
    float2* P1 = PS;           // conv1: 16*8*64  = 8192
    float2* P2 = PS + 8192;    // conv2: 16*16*16 = 4096
    float2* P3 = PS + 12288;   // conv3: 16*32*16 = 8192
    float2* P4 = PS + 20480;   // conv4: 16*16*16 = 4096
    float2* P5 = PS + 24576;   // convT: 16*8*64  = 8192
    float* out = (float*)d_out;

    pack_all<<<3436, 256, 0, stream>>>(W1, W2, W3, W4, Wt, W6, WP);

    // DWT: x -> U (A0 [16,128,128,32])
    dwt_nhwc<<<1024, 256, 0, stream>>>(x, Kd, U);

    // conv1 32->64 @128x128: U -> V (raw), partials P1
    conv_mfma<32, 64, 128, 128, true, false, 16>
        <<<1024, 256, 0, stream>>>(U, wp1, b1, V, P1, nullptr, nullptr, nullptr, 0.f);

    // conv2 (parity, GN1 in) 64->128 s2: V -> U, partials P2
    conv2p_mfma<<<512, 256, 0, stream>>>(V, wp2, b2, U, P2,
                                         P1, g1, be1, 1.f / 131072.f);

    // conv3 (GN2 in) 128->256 @64x64: U -> V, partials P3
    conv_mfma<128, 256, 64, 64, true, true, 16>
        <<<1024, 256, 0, stream>>>(U, wp3, b3, V, P3,
                                   P2, g2, be2, 1.f / 32768.f);

    // conv4 (GN3 in) 256->128 @64x64: V -> U, partials P4
    conv_mfma<256, 128, 64, 64, true, true, 16>
        <<<512, 256, 0, stream>>>(V, wp4, b4, U, P4,
                                  P3, g3, be3, 1.f / 32768.f);

    // convT (GN4 in) 128->64 x2: U -> V, partials P5
    convt_mfma<<<1024, 256, 0, stream>>>(U, wpt, bt, V, P5,
                                         P4, g4, be4, 1.f / 32768.f);

    // conv6 (GN5 in) 64->16 @128x128: V -> U (bf16 [16,128,128,16])
    conv_mfma<64, 16, 128, 128, false, true, 64>
        <<<1024, 256, 0, stream>>>(V, wp6, b6, U, nullptr,
                                   P5, g5, be5, 1.f / 131072.f);

    // IDWT: U -> out
    idwt_nhwc<<<1024, 256, 0, stream>>>(U, Kr, out);
}